// Round 6
// baseline (458.131 us; speedup 1.0000x reference)
//
#include <hip/hip_runtime.h>
#include <hip/hip_bf16.h>

// ---------------------------------------------------------------------------
// Task1_bf_final_CSW2D round 6:
//  - beamform: hw sin/cos in revolutions (FS = 4*FDEMOD exactly), fused
//    per-pixel sum over e (drops x0c buffer + k_final's x read)
//  - conv1: contiguous uint4 B-loads (R2==R3 proved misaligned dwordx4 ok)
//  - conv23: no __syncthreads in K-loop (per-wave private LDS, DS in-order)
//  - k_final: global max via order-preserving encoded atomicMax (one less
//    kernel); k_zero + k_nrm fused.
// ---------------------------------------------------------------------------

#define E_    128
#define NPIX  32768
#define NS_   (NPIX * E_)
#define NSAMP 2048

static constexpr double PI_D     = 3.14159265358979323846;
static constexpr double FS_D     = 20832000.0;
static constexpr double FDEMOD_D = 5208000.0;
static constexpr double C_D      = 1540.0;

typedef __attribute__((ext_vector_type(8))) short short8;
typedef __attribute__((ext_vector_type(4))) float f32x4;

union U8 { uint4 u4; unsigned u32[4]; unsigned short us[8]; short8 s8; };

__device__ __forceinline__ unsigned short f2bf(float f) {
  unsigned u = __float_as_uint(f);
  unsigned r = (u + 0x7fffu + ((u >> 16) & 1u)) >> 16;
  return (unsigned short)r;
}
__device__ __forceinline__ float bflo(unsigned w) { return __uint_as_float(w << 16); }
__device__ __forceinline__ float bfhi(unsigned w) { return __uint_as_float(w & 0xFFFF0000u); }

__device__ __forceinline__ float wave_reduce_sum(float v) {
  #pragma unroll
  for (int off = 32; off; off >>= 1) v += __shfl_xor(v, off);
  return v;
}
__device__ __forceinline__ float wave_reduce_max(float v) {
  #pragma unroll
  for (int off = 32; off; off >>= 1) v = fmaxf(v, __shfl_xor(v, off));
  return v;
}

// order-preserving float<->uint encode for atomicMax over signed floats
__device__ __forceinline__ unsigned enc_f(float f) {
  unsigned u = __float_as_uint(f);
  return (u >> 31) ? ~u : (u | 0x80000000u);
}
__device__ __forceinline__ float dec_f(unsigned e) {
  return (e >> 31) ? __uint_as_float(e & 0x7FFFFFFFu) : __uint_as_float(~e);
}

// BN+relu one 16B unit (8 channels of one e), repack to bf16
__device__ __forceinline__ uint4 bn_unit(uint4 v, const float* A, const float* B) {
  U8 in; in.u4 = v;
  U8 out;
  #pragma unroll
  for (int w = 0; w < 4; ++w) {
    const unsigned wd = in.u32[w];
    const float yl = fmaxf(0.f, fmaf(A[2 * w], bflo(wd), B[2 * w]));
    const float yh = fmaxf(0.f, fmaf(A[2 * w + 1], bfhi(wd), B[2 * w + 1]));
    out.us[2 * w] = f2bf(yl);
    out.us[2 * w + 1] = f2bf(yh);
  }
  return out.u4;
}

// ---------------------------------------------------------------------------
// init: zero x0p halos + global max of i^2+q^2 (maxsq pre-zeroed by memset)
// ---------------------------------------------------------------------------
__global__ __launch_bounds__(256) void k_init(uint4* __restrict__ x0p,
                                              const float* __restrict__ id,
                                              const float* __restrict__ qd,
                                              unsigned* __restrict__ maxsq) {
  const int idx = blockIdx.x * 256 + threadIdx.x;
  const int row = idx >> 5, k = idx & 31;
  if (k < 20) {
    const int q = (k < 8) ? k : (40 + (k - 8));   // uint4 0..7 and 40..51
    x0p[(size_t)row * 52 + q] = make_uint4(0, 0, 0, 0);
  }
  const int total = 16 * 128 * 2048;
  float m = 0.f;
  for (int i = idx; i < total; i += gridDim.x * 256) {
    float iv = id[i], qv = qd[i];
    m = fmaxf(m, iv * iv + qv * qv);
  }
  m = wave_reduce_max(m);
  __shared__ float sm[4];
  if ((threadIdx.x & 63) == 0) sm[threadIdx.x >> 6] = m;
  __syncthreads();
  if (threadIdx.x == 0) {
    float mm = fmaxf(fmaxf(sm[0], sm[1]), fmaxf(sm[2], sm[3]));
    atomicMax(maxsq, __float_as_uint(mm));
  }
}

// ---------------------------------------------------------------------------
// beamform -> x0p (padded, conv1 input) + per-pixel sums over e (for final)
// ---------------------------------------------------------------------------
__global__ __launch_bounds__(256) void k_beamform(
    const float* __restrict__ idata, const float* __restrict__ qdata,
    const float* __restrict__ angles, const float* __restrict__ ele_pos,
    const float* __restrict__ time_zero, const float* __restrict__ grid,
    const unsigned int* __restrict__ maxsq,
    unsigned* __restrict__ x0p,
    float* __restrict__ sumI, float* __restrict__ sumQ) {
  const int e = threadIdx.x & 127;
  const int p = blockIdx.x * 2 + (threadIdx.x >> 7);

  const float inv = 1.0f / sqrtf(__uint_as_float(*maxsq));
  const float px = grid[p * 3 + 0];
  const float pz = grid[p * 3 + 2];
  const float ang = angles[0];
  const float tz  = time_zero[0];

  constexpr float SC    = (float)(FS_D / C_D);                 // samples/m
  constexpr float TH2R  = (float)(2.0 * FDEMOD_D / C_D);       // rev coeff of pz
  constexpr float TWOPI = (float)(2.0 * PI_D);

  const float sa = __sinf(ang);
  const float ca = __cosf(ang);
  const float ta = sa / ca;
  const float txdel = (px * sa + pz * ca + tz * (float)C_D) * SC;

  const float ex = ele_pos[e * 3 + 0];
  const float dx = px - ex;
  const float rxdel = sqrtf(dx * dx + pz * pz) * SC;

  const float delays = txdel + rxdel;
  const float d0 = floorf(delays);
  const float frac = delays - d0;
  const int i0 = (int)d0;

  const float* isig = idata + e * NSAMP;
  const float* qsig = qdata + e * NSAMP;
  const int c0 = min(max(i0, 0), NSAMP - 1);
  const int c1 = min(max(i0 + 1, 0), NSAMP - 1);
  const bool m0 = (i0 >= 0) && (i0 < NSAMP);
  const bool m1 = (i0 + 1 >= 0) && (i0 + 1 < NSAMP);
  const float iv0 = m0 ? isig[c0] : 0.f;
  const float iv1 = m1 ? isig[c1] : 0.f;
  const float qv0 = m0 ? qsig[c0] : 0.f;
  const float qv1 = m1 ? qsig[c1] : 0.f;
  const float ifoc = (iv0 * (1.f - frac) + iv1 * frac) * inv;
  const float qfoc = (qv0 * (1.f - frac) + qv1 * frac) * inv;

  // theta/2pi = delays*0.25 - pz*TH2R  (exact: FS = 4*FDEMOD)
  const float trev = fmaf(delays, 0.25f, -pz * TH2R);
  const float fr = trev - floorf(trev);
  const float st = __sinf(fr * TWOPI);
  const float ct = __cosf(fr * TWOPI);
  const float ir = ifoc * ct - qfoc * st;
  const float qr = qfoc * ct + ifoc * st;

  const float ex0 = ele_pos[0];
  const float exl = ele_pos[127 * 3];
  const float avx = fabsf(dx);
  const bool mrx = (fabsf(pz) > avx) || (avx <= 0.001f) ||
                   ((dx >= 0.001f) && (px <= ex0)) ||
                   ((dx <= -0.001f) && (px >= exl));
  const float xproj = px - pz * ta;
  const bool mtx = (xproj >= ex0 * 1.2f) && (xproj <= exl * 1.2f);
  const float a = (mrx && mtx) ? 1.f : 0.f;

  const float iv = ir * a, qv = qr * a;
  x0p[(size_t)p * 208 + 32 + e] = (unsigned)f2bf(iv) | ((unsigned)f2bf(qv) << 16);

  // per-pixel sums over e (two waves per p)
  float si = wave_reduce_sum(iv);
  float sq = wave_reduce_sum(qv);
  __shared__ float sred[4][2];
  if ((threadIdx.x & 63) == 0) {
    sred[threadIdx.x >> 6][0] = si;
    sred[threadIdx.x >> 6][1] = sq;
  }
  __syncthreads();
  if ((threadIdx.x & 127) == 0) {
    const int w0 = (threadIdx.x >> 7) * 2;
    sumI[p] = sred[w0][0] + sred[w0 + 1][0];
    sumQ[p] = sred[w0][1] + sred[w0 + 1][1];
  }
}

// ---------------------------------------------------------------------------
// conv1: IC=2, K=65, pad=32, OC=8.  MFMA, taps padded to 80 (5 mfma / tile).
// Fragment element (kq, j): tap = m*16 + kq*4 + (j>>1), i = j&1 ->
// B fragment = ONE contiguous uint4 at slot t*16+n+kq*4+m*16 (4B-aligned
// dwordx4: verified OK on gfx950 — R2 and R3 produced identical bits).
// Output: compact [p][128][8ch] (16B per e).
// ---------------------------------------------------------------------------
__global__ __launch_bounds__(256) void k_conv1(
    const unsigned* __restrict__ x0p, const float* __restrict__ wgt,
    const float* __restrict__ bias, uint2* __restrict__ outp,
    float* __restrict__ partial) {
  const int tid = threadIdx.x;
  const int lane = tid & 63;
  const int wv = tid >> 6;
  const int gw = blockIdx.x * 4 + wv;         // 8192 waves
  const int n = lane & 15, kq = lane >> 4;

  // A fragments: element j -> tap = m*16 + kq*4 + (j>>1), i = j&1
  short8 af[5];
  #pragma unroll
  for (int m = 0; m < 5; ++m) {
    U8 u;
    #pragma unroll
    for (int j = 0; j < 8; ++j) {
      const int tap = m * 16 + kq * 4 + (j >> 1);
      const int i = j & 1;
      const float w = (n < 8 && tap < 65) ? wgt[(n * 2 + i) * 65 + tap] : 0.f;
      u.us[j] = f2bf(w);
    }
    af[m] = u.s8;
  }
  float bias_r[4];
  #pragma unroll
  for (int r = 0; r < 4; ++r) {
    const int oo = kq * 4 + r;
    bias_r[r] = (oo < 8) ? bias[oo] : 0.f;
  }

  float sum[4] = {0, 0, 0, 0}, ssq[4] = {0, 0, 0, 0};

  for (int p = gw; p < NPIX; p += 8192) {
    const unsigned* row = x0p + (size_t)p * 208;
    uint2* orow = outp + (size_t)p * 256;
    for (int t = 0; t < 8; ++t) {
      f32x4 acc = {bias_r[0], bias_r[1], bias_r[2], bias_r[3]};
      const int base = t * 16 + n + kq * 4;
      #pragma unroll
      for (int m = 0; m < 5; ++m) {
        U8 b;
        b.u4 = *(const uint4*)(row + base + m * 16);
        acc = __builtin_amdgcn_mfma_f32_16x16x32_bf16(af[m], b.s8, acc, 0, 0, 0);
      }
      if (lane < 32) {
        const unsigned lo = (unsigned)f2bf(acc[0]) | ((unsigned)f2bf(acc[1]) << 16);
        const unsigned hi = (unsigned)f2bf(acc[2]) | ((unsigned)f2bf(acc[3]) << 16);
        orow[(t * 16 + n) * 2 + kq] = make_uint2(lo, hi);
        #pragma unroll
        for (int r = 0; r < 4; ++r) { const float v = acc[r]; sum[r] += v; ssq[r] += v * v; }
      }
    }
  }

  #pragma unroll
  for (int off = 1; off <= 8; off <<= 1)
    #pragma unroll
    for (int r = 0; r < 4; ++r) { sum[r] += __shfl_xor(sum[r], off); ssq[r] += __shfl_xor(ssq[r], off); }
  __shared__ float s_red[4][16];
  if (lane == 0)
    #pragma unroll
    for (int r = 0; r < 4; ++r) { s_red[wv][r] = sum[r]; s_red[wv][8 + r] = ssq[r]; }
  if (lane == 16)
    #pragma unroll
    for (int r = 0; r < 4; ++r) { s_red[wv][4 + r] = sum[r]; s_red[wv][12 + r] = ssq[r]; }
  __syncthreads();
  if (tid < 16)
    partial[blockIdx.x * 16 + tid] =
        s_red[0][tid] + s_red[1][tid] + s_red[2][tid] + s_red[3][tid];
}

// ---------------------------------------------------------------------------
// conv2/3: IC=8, K=15, pad=7, OC=8.  Per-wave PRIVATE LDS row staging (no
// intra-loop barriers: a wave's DS ops are in-order, compiler tracks RAW).
// Stage: BN+relu+repack once per element into slots 7..134, halos 0..6 &
// 135..143 zeroed once (pad AFTER BN+relu).  Fragments: ds_read_b128.
// ---------------------------------------------------------------------------
__global__ __launch_bounds__(256) void k_conv23(
    const uint4* __restrict__ inp, const float* __restrict__ wgt,
    const float* __restrict__ bias, const float* __restrict__ bnAB,
    uint2* __restrict__ outp, float* __restrict__ partial) {
  __shared__ uint4 s_row[4][144];
  const int tid = threadIdx.x;
  const int lane = tid & 63;
  const int wv = tid >> 6;
  const int gw = blockIdx.x * 4 + wv;
  const int n = lane & 15, kq = lane >> 4;

  float A[8], Bc[8];
  #pragma unroll
  for (int i = 0; i < 8; ++i) { A[i] = bnAB[2 * i]; Bc[i] = bnAB[2 * i + 1]; }

  // A fragments: element j -> tap = m*4 + kq, i = j
  short8 af[4];
  #pragma unroll
  for (int m = 0; m < 4; ++m) {
    U8 u;
    #pragma unroll
    for (int j = 0; j < 8; ++j) {
      const int tap = m * 4 + kq;
      const float w = (n < 8 && tap < 15) ? wgt[(n * 8 + j) * 15 + tap] : 0.f;
      u.us[j] = f2bf(w);
    }
    af[m] = u.s8;
  }
  float bias_r[4];
  #pragma unroll
  for (int r = 0; r < 4; ++r) {
    const int oo = kq * 4 + r;
    bias_r[r] = (oo < 8) ? bias[oo] : 0.f;
  }

  uint4* lds = s_row[wv];
  if (lane < 7)  lds[lane] = make_uint4(0, 0, 0, 0);
  if (lane >= 7 && lane < 16) lds[128 + lane] = make_uint4(0, 0, 0, 0);

  float sum[4] = {0, 0, 0, 0}, ssq[4] = {0, 0, 0, 0};

  for (int p = gw; p < NPIX; p += 8192) {
    const uint4* grow = inp + (size_t)p * 128;
    const uint4 v0 = grow[lane];
    const uint4 v1 = grow[64 + lane];
    lds[7 + lane]  = bn_unit(v0, A, Bc);
    lds[71 + lane] = bn_unit(v1, A, Bc);

    uint2* orow = outp + (size_t)p * 256;
    for (int t = 0; t < 8; ++t) {
      f32x4 acc = {bias_r[0], bias_r[1], bias_r[2], bias_r[3]};
      const int base = t * 16 + n + kq;
      #pragma unroll
      for (int m = 0; m < 4; ++m) {
        U8 b;
        b.u4 = lds[base + m * 4];
        acc = __builtin_amdgcn_mfma_f32_16x16x32_bf16(af[m], b.s8, acc, 0, 0, 0);
      }
      if (lane < 32) {
        const unsigned lo = (unsigned)f2bf(acc[0]) | ((unsigned)f2bf(acc[1]) << 16);
        const unsigned hi = (unsigned)f2bf(acc[2]) | ((unsigned)f2bf(acc[3]) << 16);
        orow[(t * 16 + n) * 2 + kq] = make_uint2(lo, hi);
        #pragma unroll
        for (int r = 0; r < 4; ++r) { const float v = acc[r]; sum[r] += v; ssq[r] += v * v; }
      }
    }
  }

  #pragma unroll
  for (int off = 1; off <= 8; off <<= 1)
    #pragma unroll
    for (int r = 0; r < 4; ++r) { sum[r] += __shfl_xor(sum[r], off); ssq[r] += __shfl_xor(ssq[r], off); }
  __shared__ float s_red[4][16];
  if (lane == 0)
    #pragma unroll
    for (int r = 0; r < 4; ++r) { s_red[wv][r] = sum[r]; s_red[wv][8 + r] = ssq[r]; }
  if (lane == 16)
    #pragma unroll
    for (int r = 0; r < 4; ++r) { s_red[wv][4 + r] = sum[r]; s_red[wv][12 + r] = ssq[r]; }
  __syncthreads();
  if (tid < 16)
    partial[blockIdx.x * 16 + tid] =
        s_red[0][tid] + s_red[1][tid] + s_red[2][tid] + s_red[3][tid];
}

// ---------------------------------------------------------------------------
// conv4: IC=8, K=3, pad=1, OC=1.  VALU; BN3+relu fused on load; pad taps
// contribute exactly 0 (post-BN pad).  f32 out.
// ---------------------------------------------------------------------------
__global__ __launch_bounds__(256) void k_conv4(
    const uint4* __restrict__ inp, const float* __restrict__ bnAB,
    const float* __restrict__ w4, const float* __restrict__ b4,
    float* __restrict__ y4, float* __restrict__ partial) {
  const int idx = blockIdx.x * 256 + threadIdx.x;
  const int p = idx >> 7, e = idx & 127;

  float A[8], Bc[8];
  #pragma unroll
  for (int i = 0; i < 8; ++i) { A[i] = bnAB[2 * i]; Bc[i] = bnAB[2 * i + 1]; }

  float acc = b4[0];
  const uint4* row = inp + (size_t)p * 128 + e;
  #pragma unroll
  for (int kt = 0; kt < 3; ++kt) {
    const int ee = e + kt - 1;
    if (ee >= 0 && ee < E_) {
      U8 u; u.u4 = row[kt - 1];
      #pragma unroll
      for (int i = 0; i < 8; ++i) {
        const unsigned wd = u.u32[i >> 1];
        const float x = (i & 1) ? bfhi(wd) : bflo(wd);
        const float v = fmaxf(0.f, fmaf(A[i], x, Bc[i]));
        acc = fmaf(w4[i * 3 + kt], v, acc);
      }
    }
  }
  y4[idx] = acc;

  float s = wave_reduce_sum(acc);
  float ss = wave_reduce_sum(acc * acc);
  __shared__ float sm[4][2];
  if ((threadIdx.x & 63) == 0) { sm[threadIdx.x >> 6][0] = s; sm[threadIdx.x >> 6][1] = ss; }
  __syncthreads();
  if (threadIdx.x == 0) {
    partial[blockIdx.x * 2 + 0] = sm[0][0] + sm[1][0] + sm[2][0] + sm[3][0];
    partial[blockIdx.x * 2 + 1] = sm[0][1] + sm[1][1] + sm[2][1] + sm[3][1];
  }
}

// ---------------------------------------------------------------------------
// BN stats finalize: A = g*rsqrt(var+eps), B = beta - mu*A
// ---------------------------------------------------------------------------
__global__ __launch_bounds__(256) void k_stats(const float* __restrict__ partial,
                                               int nblk, int oc,
                                               const float* __restrict__ g,
                                               const float* __restrict__ beta,
                                               float* __restrict__ ssout) {
  const int o = blockIdx.x;
  float s = 0.f, ss = 0.f;
  for (int b = threadIdx.x; b < nblk; b += 256) {
    s  += partial[b * 2 * oc + o];
    ss += partial[b * 2 * oc + oc + o];
  }
  s = wave_reduce_sum(s);
  ss = wave_reduce_sum(ss);
  __shared__ float sm[4][2];
  if ((threadIdx.x & 63) == 0) { sm[threadIdx.x >> 6][0] = s; sm[threadIdx.x >> 6][1] = ss; }
  __syncthreads();
  if (threadIdx.x == 0) {
    s  = sm[0][0] + sm[1][0] + sm[2][0] + sm[3][0];
    ss = sm[0][1] + sm[1][1] + sm[2][1] + sm[3][1];
    const float count = (float)NS_;
    const float mu = s / count;
    const float var = fmaxf(ss / count - mu * mu, 0.f);
    const float Av = g[o] * rsqrtf(var + 1e-5f);
    ssout[2 * o] = Av;
    ssout[2 * o + 1] = beta[o] - mu * Av;
  }
}

// ---------------------------------------------------------------------------
// final: singleW = sum_e relu(A4*y4+B4); comp = singleW*(sum_e x)/E; dB.
// Also feeds the global max via encoded atomicMax (gmax_enc pre-zeroed).
// ---------------------------------------------------------------------------
__global__ __launch_bounds__(256) void k_final(const float* __restrict__ sumI,
                                               const float* __restrict__ sumQ,
                                               const float* __restrict__ y4,
                                               const float* __restrict__ ss4,
                                               float* __restrict__ ydb,
                                               unsigned* __restrict__ gmax_enc) {
  const int w = threadIdx.x >> 6;
  const int lane = threadIdx.x & 63;
  const int p = blockIdx.x * 4 + w;
  const float A = ss4[0], B = ss4[1];
  const size_t base = (size_t)p * E_;

  float sw = fmaxf(0.f, fmaf(A, y4[base + lane], B)) +
             fmaxf(0.f, fmaf(A, y4[base + lane + 64], B));
  sw = wave_reduce_sum(sw);

  __shared__ float s_m[4];
  if (lane == 0) {
    const float ci = sw * sumI[p] * (1.f / (float)E_);
    const float cq = sw * sumQ[p] * (1.f / (float)E_);
    const float mag = sqrtf(ci * ci + cq * cq);
    const float v = 20.f * log10f(mag + 1e-20f);
    ydb[p] = v;
    s_m[w] = v;
  }
  __syncthreads();
  if (threadIdx.x == 0) {
    const float bm = fmaxf(fmaxf(s_m[0], s_m[1]), fmaxf(s_m[2], s_m[3]));
    atomicMax(gmax_enc, enc_f(bm));
  }
}

__global__ __launch_bounds__(256) void k_sub(const float* __restrict__ ydb,
                                             const unsigned* __restrict__ gmax_enc,
                                             float* __restrict__ out) {
  const int i = blockIdx.x * 256 + threadIdx.x;
  out[i] = ydb[i] - dec_f(*gmax_enc);
}

// ---------------------------------------------------------------------------
// Workspace layout (bytes).  Region A is time-multiplexed:
//   x0p (27MB, dead after conv1) -> buf2 (67MB, dead after conv3)
//   -> y4 (16.8MB) + ydb.
// ---------------------------------------------------------------------------
static constexpr size_t OFF_A     = 0;            // 67,108,864 region
static constexpr size_t OFF_Y4    = 0;            // f32 [NS]   (in A)
static constexpr size_t OFF_YDB   = 16777216;     // f32 [NPIX] (in A)
static constexpr size_t OFF_BUF1  = 67108864;     // 67,108,864
static constexpr size_t OFF_SUMI  = 134217728;    // 131,072
static constexpr size_t OFF_SUMQ  = 134348800;    // 131,072
static constexpr size_t OFF_PART  = 134479872;    // 262,144
static constexpr size_t OFF_SS    = 134742016;    // 256
static constexpr size_t OFF_MAXSQ = 134742272;    // 4
static constexpr size_t OFF_GMAXE = 134742276;    // 4

extern "C" void kernel_launch(void* const* d_in, const int* in_sizes, int n_in,
                              void* d_out, int out_size, void* d_ws, size_t ws_size,
                              hipStream_t stream) {
  const float* idata     = (const float*)d_in[0];
  const float* qdata     = (const float*)d_in[1];
  const float* angles    = (const float*)d_in[2];
  const float* ele_pos   = (const float*)d_in[3];
  const float* time_zero = (const float*)d_in[4];
  const float* grid      = (const float*)d_in[5];
  const float* w1 = (const float*)d_in[6];  const float* b1 = (const float*)d_in[7];
  const float* g1 = (const float*)d_in[8];  const float* be1 = (const float*)d_in[9];
  const float* w2 = (const float*)d_in[10]; const float* b2 = (const float*)d_in[11];
  const float* g2 = (const float*)d_in[12]; const float* be2 = (const float*)d_in[13];
  const float* w3 = (const float*)d_in[14]; const float* b3 = (const float*)d_in[15];
  const float* g3 = (const float*)d_in[16]; const float* be3 = (const float*)d_in[17];
  const float* w4 = (const float*)d_in[18]; const float* b4 = (const float*)d_in[19];
  const float* g4 = (const float*)d_in[20]; const float* be4 = (const float*)d_in[21];

  char* ws = (char*)d_ws;
  unsigned*     x0p   = (unsigned*)(ws + OFF_A);       // [p][208] bf16-pairs
  uint4*        buf2  = (uint4*)(ws + OFF_A);          // [p][128] units
  float*        y4    = (float*)(ws + OFF_Y4);
  float*        ydb   = (float*)(ws + OFF_YDB);
  uint4*        buf1  = (uint4*)(ws + OFF_BUF1);
  float*        sumI  = (float*)(ws + OFF_SUMI);
  float*        sumQ  = (float*)(ws + OFF_SUMQ);
  float*        part  = (float*)(ws + OFF_PART);
  float*        ssAB  = (float*)(ws + OFF_SS);
  unsigned int* maxsq = (unsigned int*)(ws + OFF_MAXSQ);
  unsigned int* gmaxe = (unsigned int*)(ws + OFF_GMAXE);

  hipMemsetAsync(maxsq, 0, 8, stream);   // maxsq + gmax_enc

  k_init<<<4096, 256, 0, stream>>>((uint4*)x0p, idata, qdata, maxsq);
  k_beamform<<<NPIX / 2, 256, 0, stream>>>(idata, qdata, angles, ele_pos,
                                           time_zero, grid, maxsq, x0p, sumI, sumQ);

  k_conv1<<<2048, 256, 0, stream>>>(x0p, w1, b1, (uint2*)buf1, part);
  k_stats<<<8, 256, 0, stream>>>(part, 2048, 8, g1, be1, ssAB + 0);

  k_conv23<<<2048, 256, 0, stream>>>(buf1, w2, b2, ssAB + 0, (uint2*)buf2, part);
  k_stats<<<8, 256, 0, stream>>>(part, 2048, 8, g2, be2, ssAB + 16);

  k_conv23<<<2048, 256, 0, stream>>>(buf2, w3, b3, ssAB + 16, (uint2*)buf1, part);
  k_stats<<<8, 256, 0, stream>>>(part, 2048, 8, g3, be3, ssAB + 32);

  k_conv4<<<NS_ / 256, 256, 0, stream>>>(buf1, ssAB + 32, w4, b4, y4, part);
  k_stats<<<1, 256, 0, stream>>>(part, NS_ / 256, 1, g4, be4, ssAB + 48);

  k_final<<<NPIX / 4, 256, 0, stream>>>(sumI, sumQ, y4, ssAB + 48, ydb, gmaxe);
  k_sub<<<NPIX / 256, 256, 0, stream>>>(ydb, gmaxe, (float*)d_out);
}

// Round 7
// 373.987 us; speedup vs baseline: 1.2250x; 1.2250x over previous
//
#include <hip/hip_runtime.h>
#include <hip/hip_bf16.h>

// ---------------------------------------------------------------------------
// Task1_bf_final_CSW2D round 7: R6 minus the atomicMax contention.
// R6 counters: k_final 96us, VALUBusy 5%, HBM 1.3% -> 8192 same-address
// device atomics serialized in L2.  Reverted to per-block pmax[] + k_maxred
// (R5-proven, contention-free).  Everything else unchanged from R6.
// ---------------------------------------------------------------------------

#define E_    128
#define NPIX  32768
#define NS_   (NPIX * E_)
#define NSAMP 2048

static constexpr double PI_D     = 3.14159265358979323846;
static constexpr double FS_D     = 20832000.0;
static constexpr double FDEMOD_D = 5208000.0;
static constexpr double C_D      = 1540.0;

typedef __attribute__((ext_vector_type(8))) short short8;
typedef __attribute__((ext_vector_type(4))) float f32x4;

union U8 { uint4 u4; unsigned u32[4]; unsigned short us[8]; short8 s8; };

__device__ __forceinline__ unsigned short f2bf(float f) {
  unsigned u = __float_as_uint(f);
  unsigned r = (u + 0x7fffu + ((u >> 16) & 1u)) >> 16;
  return (unsigned short)r;
}
__device__ __forceinline__ float bflo(unsigned w) { return __uint_as_float(w << 16); }
__device__ __forceinline__ float bfhi(unsigned w) { return __uint_as_float(w & 0xFFFF0000u); }

__device__ __forceinline__ float wave_reduce_sum(float v) {
  #pragma unroll
  for (int off = 32; off; off >>= 1) v += __shfl_xor(v, off);
  return v;
}
__device__ __forceinline__ float wave_reduce_max(float v) {
  #pragma unroll
  for (int off = 32; off; off >>= 1) v = fmaxf(v, __shfl_xor(v, off));
  return v;
}

// BN+relu one 16B unit (8 channels of one e), repack to bf16
__device__ __forceinline__ uint4 bn_unit(uint4 v, const float* A, const float* B) {
  U8 in; in.u4 = v;
  U8 out;
  #pragma unroll
  for (int w = 0; w < 4; ++w) {
    const unsigned wd = in.u32[w];
    const float yl = fmaxf(0.f, fmaf(A[2 * w], bflo(wd), B[2 * w]));
    const float yh = fmaxf(0.f, fmaf(A[2 * w + 1], bfhi(wd), B[2 * w + 1]));
    out.us[2 * w] = f2bf(yl);
    out.us[2 * w + 1] = f2bf(yh);
  }
  return out.u4;
}

// ---------------------------------------------------------------------------
// init: zero x0p halos + global max of i^2+q^2 (maxsq pre-zeroed by memset)
// ---------------------------------------------------------------------------
__global__ __launch_bounds__(256) void k_init(uint4* __restrict__ x0p,
                                              const float* __restrict__ id,
                                              const float* __restrict__ qd,
                                              unsigned* __restrict__ maxsq) {
  const int idx = blockIdx.x * 256 + threadIdx.x;
  const int row = idx >> 5, k = idx & 31;
  if (k < 20) {
    const int q = (k < 8) ? k : (40 + (k - 8));   // uint4 0..7 and 40..51
    x0p[(size_t)row * 52 + q] = make_uint4(0, 0, 0, 0);
  }
  const int total = 16 * 128 * 2048;
  float m = 0.f;
  for (int i = idx; i < total; i += gridDim.x * 256) {
    float iv = id[i], qv = qd[i];
    m = fmaxf(m, iv * iv + qv * qv);
  }
  m = wave_reduce_max(m);
  __shared__ float sm[4];
  if ((threadIdx.x & 63) == 0) sm[threadIdx.x >> 6] = m;
  __syncthreads();
  if (threadIdx.x == 0) {
    float mm = fmaxf(fmaxf(sm[0], sm[1]), fmaxf(sm[2], sm[3]));
    atomicMax(maxsq, __float_as_uint(mm));   // nonneg floats: uint order == float order
  }
}

// ---------------------------------------------------------------------------
// beamform -> x0p (padded, conv1 input) + per-pixel sums over e (for final)
// ---------------------------------------------------------------------------
__global__ __launch_bounds__(256) void k_beamform(
    const float* __restrict__ idata, const float* __restrict__ qdata,
    const float* __restrict__ angles, const float* __restrict__ ele_pos,
    const float* __restrict__ time_zero, const float* __restrict__ grid,
    const unsigned int* __restrict__ maxsq,
    unsigned* __restrict__ x0p,
    float* __restrict__ sumI, float* __restrict__ sumQ) {
  const int e = threadIdx.x & 127;
  const int p = blockIdx.x * 2 + (threadIdx.x >> 7);

  const float inv = 1.0f / sqrtf(__uint_as_float(*maxsq));
  const float px = grid[p * 3 + 0];
  const float pz = grid[p * 3 + 2];
  const float ang = angles[0];
  const float tz  = time_zero[0];

  constexpr float SC    = (float)(FS_D / C_D);                 // samples/m
  constexpr float TH2R  = (float)(2.0 * FDEMOD_D / C_D);       // rev coeff of pz
  constexpr float TWOPI = (float)(2.0 * PI_D);

  const float sa = __sinf(ang);
  const float ca = __cosf(ang);
  const float ta = sa / ca;
  const float txdel = (px * sa + pz * ca + tz * (float)C_D) * SC;

  const float ex = ele_pos[e * 3 + 0];
  const float dx = px - ex;
  const float rxdel = sqrtf(dx * dx + pz * pz) * SC;

  const float delays = txdel + rxdel;
  const float d0 = floorf(delays);
  const float frac = delays - d0;
  const int i0 = (int)d0;

  const float* isig = idata + e * NSAMP;
  const float* qsig = qdata + e * NSAMP;
  const int c0 = min(max(i0, 0), NSAMP - 1);
  const int c1 = min(max(i0 + 1, 0), NSAMP - 1);
  const bool m0 = (i0 >= 0) && (i0 < NSAMP);
  const bool m1 = (i0 + 1 >= 0) && (i0 + 1 < NSAMP);
  const float iv0 = m0 ? isig[c0] : 0.f;
  const float iv1 = m1 ? isig[c1] : 0.f;
  const float qv0 = m0 ? qsig[c0] : 0.f;
  const float qv1 = m1 ? qsig[c1] : 0.f;
  const float ifoc = (iv0 * (1.f - frac) + iv1 * frac) * inv;
  const float qfoc = (qv0 * (1.f - frac) + qv1 * frac) * inv;

  // theta/2pi = delays*0.25 - pz*TH2R  (exact: FS = 4*FDEMOD)
  const float trev = fmaf(delays, 0.25f, -pz * TH2R);
  const float fr = trev - floorf(trev);
  const float st = __sinf(fr * TWOPI);
  const float ct = __cosf(fr * TWOPI);
  const float ir = ifoc * ct - qfoc * st;
  const float qr = qfoc * ct + ifoc * st;

  const float ex0 = ele_pos[0];
  const float exl = ele_pos[127 * 3];
  const float avx = fabsf(dx);
  const bool mrx = (fabsf(pz) > avx) || (avx <= 0.001f) ||
                   ((dx >= 0.001f) && (px <= ex0)) ||
                   ((dx <= -0.001f) && (px >= exl));
  const float xproj = px - pz * ta;
  const bool mtx = (xproj >= ex0 * 1.2f) && (xproj <= exl * 1.2f);
  const float a = (mrx && mtx) ? 1.f : 0.f;

  const float iv = ir * a, qv = qr * a;
  x0p[(size_t)p * 208 + 32 + e] = (unsigned)f2bf(iv) | ((unsigned)f2bf(qv) << 16);

  // per-pixel sums over e (two waves per p)
  float si = wave_reduce_sum(iv);
  float sq = wave_reduce_sum(qv);
  __shared__ float sred[4][2];
  if ((threadIdx.x & 63) == 0) {
    sred[threadIdx.x >> 6][0] = si;
    sred[threadIdx.x >> 6][1] = sq;
  }
  __syncthreads();
  if ((threadIdx.x & 127) == 0) {
    const int w0 = (threadIdx.x >> 7) * 2;
    sumI[p] = sred[w0][0] + sred[w0 + 1][0];
    sumQ[p] = sred[w0][1] + sred[w0 + 1][1];
  }
}

// ---------------------------------------------------------------------------
// conv1: IC=2, K=65, pad=32, OC=8.  MFMA, taps padded to 80 (5 mfma / tile).
// Fragment element (kq, j): tap = m*16 + kq*4 + (j>>1), i = j&1 ->
// B fragment = ONE contiguous uint4 (4B-aligned dwordx4 is fine on gfx950).
// Output: compact [p][128][8ch] (16B per e).
// ---------------------------------------------------------------------------
__global__ __launch_bounds__(256) void k_conv1(
    const unsigned* __restrict__ x0p, const float* __restrict__ wgt,
    const float* __restrict__ bias, uint2* __restrict__ outp,
    float* __restrict__ partial) {
  const int tid = threadIdx.x;
  const int lane = tid & 63;
  const int wv = tid >> 6;
  const int gw = blockIdx.x * 4 + wv;         // 8192 waves
  const int n = lane & 15, kq = lane >> 4;

  short8 af[5];
  #pragma unroll
  for (int m = 0; m < 5; ++m) {
    U8 u;
    #pragma unroll
    for (int j = 0; j < 8; ++j) {
      const int tap = m * 16 + kq * 4 + (j >> 1);
      const int i = j & 1;
      const float w = (n < 8 && tap < 65) ? wgt[(n * 2 + i) * 65 + tap] : 0.f;
      u.us[j] = f2bf(w);
    }
    af[m] = u.s8;
  }
  float bias_r[4];
  #pragma unroll
  for (int r = 0; r < 4; ++r) {
    const int oo = kq * 4 + r;
    bias_r[r] = (oo < 8) ? bias[oo] : 0.f;
  }

  float sum[4] = {0, 0, 0, 0}, ssq[4] = {0, 0, 0, 0};

  for (int p = gw; p < NPIX; p += 8192) {
    const unsigned* row = x0p + (size_t)p * 208;
    uint2* orow = outp + (size_t)p * 256;
    for (int t = 0; t < 8; ++t) {
      f32x4 acc = {bias_r[0], bias_r[1], bias_r[2], bias_r[3]};
      const int base = t * 16 + n + kq * 4;
      #pragma unroll
      for (int m = 0; m < 5; ++m) {
        U8 b;
        b.u4 = *(const uint4*)(row + base + m * 16);
        acc = __builtin_amdgcn_mfma_f32_16x16x32_bf16(af[m], b.s8, acc, 0, 0, 0);
      }
      if (lane < 32) {
        const unsigned lo = (unsigned)f2bf(acc[0]) | ((unsigned)f2bf(acc[1]) << 16);
        const unsigned hi = (unsigned)f2bf(acc[2]) | ((unsigned)f2bf(acc[3]) << 16);
        orow[(t * 16 + n) * 2 + kq] = make_uint2(lo, hi);
        #pragma unroll
        for (int r = 0; r < 4; ++r) { const float v = acc[r]; sum[r] += v; ssq[r] += v * v; }
      }
    }
  }

  #pragma unroll
  for (int off = 1; off <= 8; off <<= 1)
    #pragma unroll
    for (int r = 0; r < 4; ++r) { sum[r] += __shfl_xor(sum[r], off); ssq[r] += __shfl_xor(ssq[r], off); }
  __shared__ float s_red[4][16];
  if (lane == 0)
    #pragma unroll
    for (int r = 0; r < 4; ++r) { s_red[wv][r] = sum[r]; s_red[wv][8 + r] = ssq[r]; }
  if (lane == 16)
    #pragma unroll
    for (int r = 0; r < 4; ++r) { s_red[wv][4 + r] = sum[r]; s_red[wv][12 + r] = ssq[r]; }
  __syncthreads();
  if (tid < 16)
    partial[blockIdx.x * 16 + tid] =
        s_red[0][tid] + s_red[1][tid] + s_red[2][tid] + s_red[3][tid];
}

// ---------------------------------------------------------------------------
// conv2/3: IC=8, K=15, pad=7, OC=8.  Per-wave PRIVATE LDS row staging (no
// intra-loop barriers).  Stage: BN+relu+repack once per element into slots
// 7..134, halos zeroed once (pad AFTER BN+relu).  Fragments: ds_read_b128.
// ---------------------------------------------------------------------------
__global__ __launch_bounds__(256) void k_conv23(
    const uint4* __restrict__ inp, const float* __restrict__ wgt,
    const float* __restrict__ bias, const float* __restrict__ bnAB,
    uint2* __restrict__ outp, float* __restrict__ partial) {
  __shared__ uint4 s_row[4][144];
  const int tid = threadIdx.x;
  const int lane = tid & 63;
  const int wv = tid >> 6;
  const int gw = blockIdx.x * 4 + wv;
  const int n = lane & 15, kq = lane >> 4;

  float A[8], Bc[8];
  #pragma unroll
  for (int i = 0; i < 8; ++i) { A[i] = bnAB[2 * i]; Bc[i] = bnAB[2 * i + 1]; }

  short8 af[4];
  #pragma unroll
  for (int m = 0; m < 4; ++m) {
    U8 u;
    #pragma unroll
    for (int j = 0; j < 8; ++j) {
      const int tap = m * 4 + kq;
      const float w = (n < 8 && tap < 15) ? wgt[(n * 8 + j) * 15 + tap] : 0.f;
      u.us[j] = f2bf(w);
    }
    af[m] = u.s8;
  }
  float bias_r[4];
  #pragma unroll
  for (int r = 0; r < 4; ++r) {
    const int oo = kq * 4 + r;
    bias_r[r] = (oo < 8) ? bias[oo] : 0.f;
  }

  uint4* lds = s_row[wv];
  if (lane < 7)  lds[lane] = make_uint4(0, 0, 0, 0);
  if (lane >= 7 && lane < 16) lds[128 + lane] = make_uint4(0, 0, 0, 0);

  float sum[4] = {0, 0, 0, 0}, ssq[4] = {0, 0, 0, 0};

  for (int p = gw; p < NPIX; p += 8192) {
    const uint4* grow = inp + (size_t)p * 128;
    const uint4 v0 = grow[lane];
    const uint4 v1 = grow[64 + lane];
    lds[7 + lane]  = bn_unit(v0, A, Bc);
    lds[71 + lane] = bn_unit(v1, A, Bc);

    uint2* orow = outp + (size_t)p * 256;
    for (int t = 0; t < 8; ++t) {
      f32x4 acc = {bias_r[0], bias_r[1], bias_r[2], bias_r[3]};
      const int base = t * 16 + n + kq;
      #pragma unroll
      for (int m = 0; m < 4; ++m) {
        U8 b;
        b.u4 = lds[base + m * 4];
        acc = __builtin_amdgcn_mfma_f32_16x16x32_bf16(af[m], b.s8, acc, 0, 0, 0);
      }
      if (lane < 32) {
        const unsigned lo = (unsigned)f2bf(acc[0]) | ((unsigned)f2bf(acc[1]) << 16);
        const unsigned hi = (unsigned)f2bf(acc[2]) | ((unsigned)f2bf(acc[3]) << 16);
        orow[(t * 16 + n) * 2 + kq] = make_uint2(lo, hi);
        #pragma unroll
        for (int r = 0; r < 4; ++r) { const float v = acc[r]; sum[r] += v; ssq[r] += v * v; }
      }
    }
  }

  #pragma unroll
  for (int off = 1; off <= 8; off <<= 1)
    #pragma unroll
    for (int r = 0; r < 4; ++r) { sum[r] += __shfl_xor(sum[r], off); ssq[r] += __shfl_xor(ssq[r], off); }
  __shared__ float s_red[4][16];
  if (lane == 0)
    #pragma unroll
    for (int r = 0; r < 4; ++r) { s_red[wv][r] = sum[r]; s_red[wv][8 + r] = ssq[r]; }
  if (lane == 16)
    #pragma unroll
    for (int r = 0; r < 4; ++r) { s_red[wv][4 + r] = sum[r]; s_red[wv][12 + r] = ssq[r]; }
  __syncthreads();
  if (tid < 16)
    partial[blockIdx.x * 16 + tid] =
        s_red[0][tid] + s_red[1][tid] + s_red[2][tid] + s_red[3][tid];
}

// ---------------------------------------------------------------------------
// conv4: IC=8, K=3, pad=1, OC=1.  VALU; BN3+relu fused on load; pad taps
// contribute exactly 0 (post-BN pad).  f32 out.
// ---------------------------------------------------------------------------
__global__ __launch_bounds__(256) void k_conv4(
    const uint4* __restrict__ inp, const float* __restrict__ bnAB,
    const float* __restrict__ w4, const float* __restrict__ b4,
    float* __restrict__ y4, float* __restrict__ partial) {
  const int idx = blockIdx.x * 256 + threadIdx.x;
  const int p = idx >> 7, e = idx & 127;

  float A[8], Bc[8];
  #pragma unroll
  for (int i = 0; i < 8; ++i) { A[i] = bnAB[2 * i]; Bc[i] = bnAB[2 * i + 1]; }

  float acc = b4[0];
  const uint4* row = inp + (size_t)p * 128 + e;
  #pragma unroll
  for (int kt = 0; kt < 3; ++kt) {
    const int ee = e + kt - 1;
    if (ee >= 0 && ee < E_) {
      U8 u; u.u4 = row[kt - 1];
      #pragma unroll
      for (int i = 0; i < 8; ++i) {
        const unsigned wd = u.u32[i >> 1];
        const float x = (i & 1) ? bfhi(wd) : bflo(wd);
        const float v = fmaxf(0.f, fmaf(A[i], x, Bc[i]));
        acc = fmaf(w4[i * 3 + kt], v, acc);
      }
    }
  }
  y4[idx] = acc;

  float s = wave_reduce_sum(acc);
  float ss = wave_reduce_sum(acc * acc);
  __shared__ float sm[4][2];
  if ((threadIdx.x & 63) == 0) { sm[threadIdx.x >> 6][0] = s; sm[threadIdx.x >> 6][1] = ss; }
  __syncthreads();
  if (threadIdx.x == 0) {
    partial[blockIdx.x * 2 + 0] = sm[0][0] + sm[1][0] + sm[2][0] + sm[3][0];
    partial[blockIdx.x * 2 + 1] = sm[0][1] + sm[1][1] + sm[2][1] + sm[3][1];
  }
}

// ---------------------------------------------------------------------------
// BN stats finalize: A = g*rsqrt(var+eps), B = beta - mu*A
// ---------------------------------------------------------------------------
__global__ __launch_bounds__(256) void k_stats(const float* __restrict__ partial,
                                               int nblk, int oc,
                                               const float* __restrict__ g,
                                               const float* __restrict__ beta,
                                               float* __restrict__ ssout) {
  const int o = blockIdx.x;
  float s = 0.f, ss = 0.f;
  for (int b = threadIdx.x; b < nblk; b += 256) {
    s  += partial[b * 2 * oc + o];
    ss += partial[b * 2 * oc + oc + o];
  }
  s = wave_reduce_sum(s);
  ss = wave_reduce_sum(ss);
  __shared__ float sm[4][2];
  if ((threadIdx.x & 63) == 0) { sm[threadIdx.x >> 6][0] = s; sm[threadIdx.x >> 6][1] = ss; }
  __syncthreads();
  if (threadIdx.x == 0) {
    s  = sm[0][0] + sm[1][0] + sm[2][0] + sm[3][0];
    ss = sm[0][1] + sm[1][1] + sm[2][1] + sm[3][1];
    const float count = (float)NS_;
    const float mu = s / count;
    const float var = fmaxf(ss / count - mu * mu, 0.f);
    const float Av = g[o] * rsqrtf(var + 1e-5f);
    ssout[2 * o] = Av;
    ssout[2 * o + 1] = beta[o] - mu * Av;
  }
}

// ---------------------------------------------------------------------------
// final: singleW = sum_e relu(A4*y4+B4); comp = singleW*(sum_e x)/E; dB.
// Per-block max -> pmax[] (NO same-address atomics).
// ---------------------------------------------------------------------------
__global__ __launch_bounds__(256) void k_final(const float* __restrict__ sumI,
                                               const float* __restrict__ sumQ,
                                               const float* __restrict__ y4,
                                               const float* __restrict__ ss4,
                                               float* __restrict__ ydb,
                                               float* __restrict__ pmax) {
  const int w = threadIdx.x >> 6;
  const int lane = threadIdx.x & 63;
  const int p = blockIdx.x * 4 + w;
  const float A = ss4[0], B = ss4[1];
  const size_t base = (size_t)p * E_;

  float sw = fmaxf(0.f, fmaf(A, y4[base + lane], B)) +
             fmaxf(0.f, fmaf(A, y4[base + lane + 64], B));
  sw = wave_reduce_sum(sw);

  __shared__ float s_m[4];
  if (lane == 0) {
    const float ci = sw * sumI[p] * (1.f / (float)E_);
    const float cq = sw * sumQ[p] * (1.f / (float)E_);
    const float mag = sqrtf(ci * ci + cq * cq);
    const float v = 20.f * log10f(mag + 1e-20f);
    ydb[p] = v;
    s_m[w] = v;
  }
  __syncthreads();
  if (threadIdx.x == 0)
    pmax[blockIdx.x] = fmaxf(fmaxf(s_m[0], s_m[1]), fmaxf(s_m[2], s_m[3]));
}

__global__ __launch_bounds__(256) void k_maxred(const float* __restrict__ pmax,
                                                int n, float* __restrict__ gmax) {
  float m = -3.4e38f;
  for (int i = threadIdx.x; i < n; i += 256) m = fmaxf(m, pmax[i]);
  m = wave_reduce_max(m);
  __shared__ float sm[4];
  if ((threadIdx.x & 63) == 0) sm[threadIdx.x >> 6] = m;
  __syncthreads();
  if (threadIdx.x == 0)
    gmax[0] = fmaxf(fmaxf(sm[0], sm[1]), fmaxf(sm[2], sm[3]));
}

__global__ __launch_bounds__(256) void k_sub(const float* __restrict__ ydb,
                                             const float* __restrict__ gmax,
                                             float* __restrict__ out) {
  const int i = blockIdx.x * 256 + threadIdx.x;
  out[i] = ydb[i] - gmax[0];
}

// ---------------------------------------------------------------------------
// Workspace layout (bytes).  Region A is time-multiplexed:
//   x0p (27MB, dead after conv1) -> buf2 (67MB, dead after conv3)
//   -> y4 (16.8MB) + ydb + pmax.
// ---------------------------------------------------------------------------
static constexpr size_t OFF_A     = 0;            // 67,108,864 region
static constexpr size_t OFF_Y4    = 0;            // f32 [NS]   (in A)
static constexpr size_t OFF_YDB   = 16777216;     // f32 [NPIX] (in A)
static constexpr size_t OFF_PMAX  = 16908288;     // f32 [8192] (in A)
static constexpr size_t OFF_BUF1  = 67108864;     // 67,108,864
static constexpr size_t OFF_SUMI  = 134217728;    // 131,072
static constexpr size_t OFF_SUMQ  = 134348800;    // 131,072
static constexpr size_t OFF_PART  = 134479872;    // 262,144
static constexpr size_t OFF_SS    = 134742016;    // 256
static constexpr size_t OFF_MAXSQ = 134742272;    // 4
static constexpr size_t OFF_GMAX  = 134742276;    // 4

extern "C" void kernel_launch(void* const* d_in, const int* in_sizes, int n_in,
                              void* d_out, int out_size, void* d_ws, size_t ws_size,
                              hipStream_t stream) {
  const float* idata     = (const float*)d_in[0];
  const float* qdata     = (const float*)d_in[1];
  const float* angles    = (const float*)d_in[2];
  const float* ele_pos   = (const float*)d_in[3];
  const float* time_zero = (const float*)d_in[4];
  const float* grid      = (const float*)d_in[5];
  const float* w1 = (const float*)d_in[6];  const float* b1 = (const float*)d_in[7];
  const float* g1 = (const float*)d_in[8];  const float* be1 = (const float*)d_in[9];
  const float* w2 = (const float*)d_in[10]; const float* b2 = (const float*)d_in[11];
  const float* g2 = (const float*)d_in[12]; const float* be2 = (const float*)d_in[13];
  const float* w3 = (const float*)d_in[14]; const float* b3 = (const float*)d_in[15];
  const float* g3 = (const float*)d_in[16]; const float* be3 = (const float*)d_in[17];
  const float* w4 = (const float*)d_in[18]; const float* b4 = (const float*)d_in[19];
  const float* g4 = (const float*)d_in[20]; const float* be4 = (const float*)d_in[21];

  char* ws = (char*)d_ws;
  unsigned*     x0p   = (unsigned*)(ws + OFF_A);       // [p][208] bf16-pairs
  uint4*        buf2  = (uint4*)(ws + OFF_A);          // [p][128] units
  float*        y4    = (float*)(ws + OFF_Y4);
  float*        ydb   = (float*)(ws + OFF_YDB);
  float*        pmax  = (float*)(ws + OFF_PMAX);
  uint4*        buf1  = (uint4*)(ws + OFF_BUF1);
  float*        sumI  = (float*)(ws + OFF_SUMI);
  float*        sumQ  = (float*)(ws + OFF_SUMQ);
  float*        part  = (float*)(ws + OFF_PART);
  float*        ssAB  = (float*)(ws + OFF_SS);
  unsigned int* maxsq = (unsigned int*)(ws + OFF_MAXSQ);
  float*        gmax  = (float*)(ws + OFF_GMAX);

  hipMemsetAsync(maxsq, 0, 4, stream);

  k_init<<<4096, 256, 0, stream>>>((uint4*)x0p, idata, qdata, maxsq);
  k_beamform<<<NPIX / 2, 256, 0, stream>>>(idata, qdata, angles, ele_pos,
                                           time_zero, grid, maxsq, x0p, sumI, sumQ);

  k_conv1<<<2048, 256, 0, stream>>>(x0p, w1, b1, (uint2*)buf1, part);
  k_stats<<<8, 256, 0, stream>>>(part, 2048, 8, g1, be1, ssAB + 0);

  k_conv23<<<2048, 256, 0, stream>>>(buf1, w2, b2, ssAB + 0, (uint2*)buf2, part);
  k_stats<<<8, 256, 0, stream>>>(part, 2048, 8, g2, be2, ssAB + 16);

  k_conv23<<<2048, 256, 0, stream>>>(buf2, w3, b3, ssAB + 16, (uint2*)buf1, part);
  k_stats<<<8, 256, 0, stream>>>(part, 2048, 8, g3, be3, ssAB + 32);

  k_conv4<<<NS_ / 256, 256, 0, stream>>>(buf1, ssAB + 32, w4, b4, y4, part);
  k_stats<<<1, 256, 0, stream>>>(part, NS_ / 256, 1, g4, be4, ssAB + 48);

  k_final<<<NPIX / 4, 256, 0, stream>>>(sumI, sumQ, y4, ssAB + 48, ydb, pmax);
  k_maxred<<<1, 256, 0, stream>>>(pmax, NPIX / 4, gmax);
  k_sub<<<NPIX / 256, 256, 0, stream>>>(ydb, gmax, (float*)d_out);
}

// Round 8
// 334.476 us; speedup vs baseline: 1.3697x; 1.1181x over previous
//
#include <hip/hip_runtime.h>
#include <hip/hip_bf16.h>

// ---------------------------------------------------------------------------
// Task1_bf_final_CSW2D round 8: kill the k_init atomicMax serialization.
// R7 counters: k_init 54us, VALUBusy 4.5%, HBM 6.3% -> 4096 same-address
// device atomics ~= 45us (same pathology as R6's k_final).  Now k_init
// writes per-block partial maxima (no atomics) + 1-block k_nrmred; max-scan
// vectorized to float4 (exactly one per thread per array).
// Everything else identical to R7.
// ---------------------------------------------------------------------------

#define E_    128
#define NPIX  32768
#define NS_   (NPIX * E_)
#define NSAMP 2048

static constexpr double PI_D     = 3.14159265358979323846;
static constexpr double FS_D     = 20832000.0;
static constexpr double FDEMOD_D = 5208000.0;
static constexpr double C_D      = 1540.0;

typedef __attribute__((ext_vector_type(8))) short short8;
typedef __attribute__((ext_vector_type(4))) float f32x4;

union U8 { uint4 u4; unsigned u32[4]; unsigned short us[8]; short8 s8; };

__device__ __forceinline__ unsigned short f2bf(float f) {
  unsigned u = __float_as_uint(f);
  unsigned r = (u + 0x7fffu + ((u >> 16) & 1u)) >> 16;
  return (unsigned short)r;
}
__device__ __forceinline__ float bflo(unsigned w) { return __uint_as_float(w << 16); }
__device__ __forceinline__ float bfhi(unsigned w) { return __uint_as_float(w & 0xFFFF0000u); }

__device__ __forceinline__ float wave_reduce_sum(float v) {
  #pragma unroll
  for (int off = 32; off; off >>= 1) v += __shfl_xor(v, off);
  return v;
}
__device__ __forceinline__ float wave_reduce_max(float v) {
  #pragma unroll
  for (int off = 32; off; off >>= 1) v = fmaxf(v, __shfl_xor(v, off));
  return v;
}

// BN+relu one 16B unit (8 channels of one e), repack to bf16
__device__ __forceinline__ uint4 bn_unit(uint4 v, const float* A, const float* B) {
  U8 in; in.u4 = v;
  U8 out;
  #pragma unroll
  for (int w = 0; w < 4; ++w) {
    const unsigned wd = in.u32[w];
    const float yl = fmaxf(0.f, fmaf(A[2 * w], bflo(wd), B[2 * w]));
    const float yh = fmaxf(0.f, fmaf(A[2 * w + 1], bfhi(wd), B[2 * w + 1]));
    out.us[2 * w] = f2bf(yl);
    out.us[2 * w + 1] = f2bf(yh);
  }
  return out.u4;
}

// ---------------------------------------------------------------------------
// init: zero x0p halos + PER-BLOCK max of i^2+q^2 (float4-vectorized,
// no atomics -> pmaxsq[block]).  4096 blocks x 256 thr; idx covers the
// 1,048,576 float4's of each input exactly once.
// ---------------------------------------------------------------------------
__global__ __launch_bounds__(256) void k_init(uint4* __restrict__ x0p,
                                              const float4* __restrict__ id4,
                                              const float4* __restrict__ qd4,
                                              float* __restrict__ pmaxsq) {
  const int idx = blockIdx.x * 256 + threadIdx.x;
  const int row = idx >> 5, k = idx & 31;
  if (k < 20) {
    const int q = (k < 8) ? k : (40 + (k - 8));   // uint4 0..7 and 40..51
    x0p[(size_t)row * 52 + q] = make_uint4(0, 0, 0, 0);
  }
  const float4 iv = id4[idx];
  const float4 qv = qd4[idx];
  float m = fmaxf(fmaxf(iv.x * iv.x + qv.x * qv.x, iv.y * iv.y + qv.y * qv.y),
                  fmaxf(iv.z * iv.z + qv.z * qv.z, iv.w * iv.w + qv.w * qv.w));
  m = wave_reduce_max(m);
  __shared__ float sm[4];
  if ((threadIdx.x & 63) == 0) sm[threadIdx.x >> 6] = m;
  __syncthreads();
  if (threadIdx.x == 0)
    pmaxsq[blockIdx.x] = fmaxf(fmaxf(sm[0], sm[1]), fmaxf(sm[2], sm[3]));
}

__global__ __launch_bounds__(256) void k_nrmred(const float* __restrict__ pmaxsq,
                                                float* __restrict__ maxsq) {
  float m = 0.f;
  for (int i = threadIdx.x; i < 4096; i += 256) m = fmaxf(m, pmaxsq[i]);
  m = wave_reduce_max(m);
  __shared__ float sm[4];
  if ((threadIdx.x & 63) == 0) sm[threadIdx.x >> 6] = m;
  __syncthreads();
  if (threadIdx.x == 0)
    maxsq[0] = fmaxf(fmaxf(sm[0], sm[1]), fmaxf(sm[2], sm[3]));
}

// ---------------------------------------------------------------------------
// beamform -> x0p (padded, conv1 input) + per-pixel sums over e (for final)
// ---------------------------------------------------------------------------
__global__ __launch_bounds__(256) void k_beamform(
    const float* __restrict__ idata, const float* __restrict__ qdata,
    const float* __restrict__ angles, const float* __restrict__ ele_pos,
    const float* __restrict__ time_zero, const float* __restrict__ grid,
    const float* __restrict__ maxsq,
    unsigned* __restrict__ x0p,
    float* __restrict__ sumI, float* __restrict__ sumQ) {
  const int e = threadIdx.x & 127;
  const int p = blockIdx.x * 2 + (threadIdx.x >> 7);

  const float inv = 1.0f / sqrtf(*maxsq);
  const float px = grid[p * 3 + 0];
  const float pz = grid[p * 3 + 2];
  const float ang = angles[0];
  const float tz  = time_zero[0];

  constexpr float SC    = (float)(FS_D / C_D);                 // samples/m
  constexpr float TH2R  = (float)(2.0 * FDEMOD_D / C_D);       // rev coeff of pz
  constexpr float TWOPI = (float)(2.0 * PI_D);

  const float sa = __sinf(ang);
  const float ca = __cosf(ang);
  const float ta = sa / ca;
  const float txdel = (px * sa + pz * ca + tz * (float)C_D) * SC;

  const float ex = ele_pos[e * 3 + 0];
  const float dx = px - ex;
  const float rxdel = sqrtf(dx * dx + pz * pz) * SC;

  const float delays = txdel + rxdel;
  const float d0 = floorf(delays);
  const float frac = delays - d0;
  const int i0 = (int)d0;

  const float* isig = idata + e * NSAMP;
  const float* qsig = qdata + e * NSAMP;
  const int c0 = min(max(i0, 0), NSAMP - 1);
  const int c1 = min(max(i0 + 1, 0), NSAMP - 1);
  const bool m0 = (i0 >= 0) && (i0 < NSAMP);
  const bool m1 = (i0 + 1 >= 0) && (i0 + 1 < NSAMP);
  const float iv0 = m0 ? isig[c0] : 0.f;
  const float iv1 = m1 ? isig[c1] : 0.f;
  const float qv0 = m0 ? qsig[c0] : 0.f;
  const float qv1 = m1 ? qsig[c1] : 0.f;
  const float ifoc = (iv0 * (1.f - frac) + iv1 * frac) * inv;
  const float qfoc = (qv0 * (1.f - frac) + qv1 * frac) * inv;

  // theta/2pi = delays*0.25 - pz*TH2R  (exact: FS = 4*FDEMOD)
  const float trev = fmaf(delays, 0.25f, -pz * TH2R);
  const float fr = trev - floorf(trev);
  const float st = __sinf(fr * TWOPI);
  const float ct = __cosf(fr * TWOPI);
  const float ir = ifoc * ct - qfoc * st;
  const float qr = qfoc * ct + ifoc * st;

  const float ex0 = ele_pos[0];
  const float exl = ele_pos[127 * 3];
  const float avx = fabsf(dx);
  const bool mrx = (fabsf(pz) > avx) || (avx <= 0.001f) ||
                   ((dx >= 0.001f) && (px <= ex0)) ||
                   ((dx <= -0.001f) && (px >= exl));
  const float xproj = px - pz * ta;
  const bool mtx = (xproj >= ex0 * 1.2f) && (xproj <= exl * 1.2f);
  const float a = (mrx && mtx) ? 1.f : 0.f;

  const float iv = ir * a, qv = qr * a;
  x0p[(size_t)p * 208 + 32 + e] = (unsigned)f2bf(iv) | ((unsigned)f2bf(qv) << 16);

  // per-pixel sums over e (two waves per p)
  float si = wave_reduce_sum(iv);
  float sq = wave_reduce_sum(qv);
  __shared__ float sred[4][2];
  if ((threadIdx.x & 63) == 0) {
    sred[threadIdx.x >> 6][0] = si;
    sred[threadIdx.x >> 6][1] = sq;
  }
  __syncthreads();
  if ((threadIdx.x & 127) == 0) {
    const int w0 = (threadIdx.x >> 7) * 2;
    sumI[p] = sred[w0][0] + sred[w0 + 1][0];
    sumQ[p] = sred[w0][1] + sred[w0 + 1][1];
  }
}

// ---------------------------------------------------------------------------
// conv1: IC=2, K=65, pad=32, OC=8.  MFMA, taps padded to 80 (5 mfma / tile).
// Fragment element (kq, j): tap = m*16 + kq*4 + (j>>1), i = j&1 ->
// B fragment = ONE contiguous uint4 (4B-aligned dwordx4 is fine on gfx950).
// Output: compact [p][128][8ch] (16B per e).
// ---------------------------------------------------------------------------
__global__ __launch_bounds__(256) void k_conv1(
    const unsigned* __restrict__ x0p, const float* __restrict__ wgt,
    const float* __restrict__ bias, uint2* __restrict__ outp,
    float* __restrict__ partial) {
  const int tid = threadIdx.x;
  const int lane = tid & 63;
  const int wv = tid >> 6;
  const int gw = blockIdx.x * 4 + wv;         // 8192 waves
  const int n = lane & 15, kq = lane >> 4;

  short8 af[5];
  #pragma unroll
  for (int m = 0; m < 5; ++m) {
    U8 u;
    #pragma unroll
    for (int j = 0; j < 8; ++j) {
      const int tap = m * 16 + kq * 4 + (j >> 1);
      const int i = j & 1;
      const float w = (n < 8 && tap < 65) ? wgt[(n * 2 + i) * 65 + tap] : 0.f;
      u.us[j] = f2bf(w);
    }
    af[m] = u.s8;
  }
  float bias_r[4];
  #pragma unroll
  for (int r = 0; r < 4; ++r) {
    const int oo = kq * 4 + r;
    bias_r[r] = (oo < 8) ? bias[oo] : 0.f;
  }

  float sum[4] = {0, 0, 0, 0}, ssq[4] = {0, 0, 0, 0};

  for (int p = gw; p < NPIX; p += 8192) {
    const unsigned* row = x0p + (size_t)p * 208;
    uint2* orow = outp + (size_t)p * 256;
    for (int t = 0; t < 8; ++t) {
      f32x4 acc = {bias_r[0], bias_r[1], bias_r[2], bias_r[3]};
      const int base = t * 16 + n + kq * 4;
      #pragma unroll
      for (int m = 0; m < 5; ++m) {
        U8 b;
        b.u4 = *(const uint4*)(row + base + m * 16);
        acc = __builtin_amdgcn_mfma_f32_16x16x32_bf16(af[m], b.s8, acc, 0, 0, 0);
      }
      if (lane < 32) {
        const unsigned lo = (unsigned)f2bf(acc[0]) | ((unsigned)f2bf(acc[1]) << 16);
        const unsigned hi = (unsigned)f2bf(acc[2]) | ((unsigned)f2bf(acc[3]) << 16);
        orow[(t * 16 + n) * 2 + kq] = make_uint2(lo, hi);
        #pragma unroll
        for (int r = 0; r < 4; ++r) { const float v = acc[r]; sum[r] += v; ssq[r] += v * v; }
      }
    }
  }

  #pragma unroll
  for (int off = 1; off <= 8; off <<= 1)
    #pragma unroll
    for (int r = 0; r < 4; ++r) { sum[r] += __shfl_xor(sum[r], off); ssq[r] += __shfl_xor(ssq[r], off); }
  __shared__ float s_red[4][16];
  if (lane == 0)
    #pragma unroll
    for (int r = 0; r < 4; ++r) { s_red[wv][r] = sum[r]; s_red[wv][8 + r] = ssq[r]; }
  if (lane == 16)
    #pragma unroll
    for (int r = 0; r < 4; ++r) { s_red[wv][4 + r] = sum[r]; s_red[wv][12 + r] = ssq[r]; }
  __syncthreads();
  if (tid < 16)
    partial[blockIdx.x * 16 + tid] =
        s_red[0][tid] + s_red[1][tid] + s_red[2][tid] + s_red[3][tid];
}

// ---------------------------------------------------------------------------
// conv2/3: IC=8, K=15, pad=7, OC=8.  Per-wave PRIVATE LDS row staging (no
// intra-loop barriers).  Stage: BN+relu+repack once per element into slots
// 7..134, halos zeroed once (pad AFTER BN+relu).  Fragments: ds_read_b128.
// ---------------------------------------------------------------------------
__global__ __launch_bounds__(256) void k_conv23(
    const uint4* __restrict__ inp, const float* __restrict__ wgt,
    const float* __restrict__ bias, const float* __restrict__ bnAB,
    uint2* __restrict__ outp, float* __restrict__ partial) {
  __shared__ uint4 s_row[4][144];
  const int tid = threadIdx.x;
  const int lane = tid & 63;
  const int wv = tid >> 6;
  const int gw = blockIdx.x * 4 + wv;
  const int n = lane & 15, kq = lane >> 4;

  float A[8], Bc[8];
  #pragma unroll
  for (int i = 0; i < 8; ++i) { A[i] = bnAB[2 * i]; Bc[i] = bnAB[2 * i + 1]; }

  short8 af[4];
  #pragma unroll
  for (int m = 0; m < 4; ++m) {
    U8 u;
    #pragma unroll
    for (int j = 0; j < 8; ++j) {
      const int tap = m * 4 + kq;
      const float w = (n < 8 && tap < 15) ? wgt[(n * 8 + j) * 15 + tap] : 0.f;
      u.us[j] = f2bf(w);
    }
    af[m] = u.s8;
  }
  float bias_r[4];
  #pragma unroll
  for (int r = 0; r < 4; ++r) {
    const int oo = kq * 4 + r;
    bias_r[r] = (oo < 8) ? bias[oo] : 0.f;
  }

  uint4* lds = s_row[wv];
  if (lane < 7)  lds[lane] = make_uint4(0, 0, 0, 0);
  if (lane >= 7 && lane < 16) lds[128 + lane] = make_uint4(0, 0, 0, 0);

  float sum[4] = {0, 0, 0, 0}, ssq[4] = {0, 0, 0, 0};

  for (int p = gw; p < NPIX; p += 8192) {
    const uint4* grow = inp + (size_t)p * 128;
    const uint4 v0 = grow[lane];
    const uint4 v1 = grow[64 + lane];
    lds[7 + lane]  = bn_unit(v0, A, Bc);
    lds[71 + lane] = bn_unit(v1, A, Bc);

    uint2* orow = outp + (size_t)p * 256;
    for (int t = 0; t < 8; ++t) {
      f32x4 acc = {bias_r[0], bias_r[1], bias_r[2], bias_r[3]};
      const int base = t * 16 + n + kq;
      #pragma unroll
      for (int m = 0; m < 4; ++m) {
        U8 b;
        b.u4 = lds[base + m * 4];
        acc = __builtin_amdgcn_mfma_f32_16x16x32_bf16(af[m], b.s8, acc, 0, 0, 0);
      }
      if (lane < 32) {
        const unsigned lo = (unsigned)f2bf(acc[0]) | ((unsigned)f2bf(acc[1]) << 16);
        const unsigned hi = (unsigned)f2bf(acc[2]) | ((unsigned)f2bf(acc[3]) << 16);
        orow[(t * 16 + n) * 2 + kq] = make_uint2(lo, hi);
        #pragma unroll
        for (int r = 0; r < 4; ++r) { const float v = acc[r]; sum[r] += v; ssq[r] += v * v; }
      }
    }
  }

  #pragma unroll
  for (int off = 1; off <= 8; off <<= 1)
    #pragma unroll
    for (int r = 0; r < 4; ++r) { sum[r] += __shfl_xor(sum[r], off); ssq[r] += __shfl_xor(ssq[r], off); }
  __shared__ float s_red[4][16];
  if (lane == 0)
    #pragma unroll
    for (int r = 0; r < 4; ++r) { s_red[wv][r] = sum[r]; s_red[wv][8 + r] = ssq[r]; }
  if (lane == 16)
    #pragma unroll
    for (int r = 0; r < 4; ++r) { s_red[wv][4 + r] = sum[r]; s_red[wv][12 + r] = ssq[r]; }
  __syncthreads();
  if (tid < 16)
    partial[blockIdx.x * 16 + tid] =
        s_red[0][tid] + s_red[1][tid] + s_red[2][tid] + s_red[3][tid];
}

// ---------------------------------------------------------------------------
// conv4: IC=8, K=3, pad=1, OC=1.  VALU; BN3+relu fused on load; pad taps
// contribute exactly 0 (post-BN pad).  f32 out.
// ---------------------------------------------------------------------------
__global__ __launch_bounds__(256) void k_conv4(
    const uint4* __restrict__ inp, const float* __restrict__ bnAB,
    const float* __restrict__ w4, const float* __restrict__ b4,
    float* __restrict__ y4, float* __restrict__ partial) {
  const int idx = blockIdx.x * 256 + threadIdx.x;
  const int p = idx >> 7, e = idx & 127;

  float A[8], Bc[8];
  #pragma unroll
  for (int i = 0; i < 8; ++i) { A[i] = bnAB[2 * i]; Bc[i] = bnAB[2 * i + 1]; }

  float acc = b4[0];
  const uint4* row = inp + (size_t)p * 128 + e;
  #pragma unroll
  for (int kt = 0; kt < 3; ++kt) {
    const int ee = e + kt - 1;
    if (ee >= 0 && ee < E_) {
      U8 u; u.u4 = row[kt - 1];
      #pragma unroll
      for (int i = 0; i < 8; ++i) {
        const unsigned wd = u.u32[i >> 1];
        const float x = (i & 1) ? bfhi(wd) : bflo(wd);
        const float v = fmaxf(0.f, fmaf(A[i], x, Bc[i]));
        acc = fmaf(w4[i * 3 + kt], v, acc);
      }
    }
  }
  y4[idx] = acc;

  float s = wave_reduce_sum(acc);
  float ss = wave_reduce_sum(acc * acc);
  __shared__ float sm[4][2];
  if ((threadIdx.x & 63) == 0) { sm[threadIdx.x >> 6][0] = s; sm[threadIdx.x >> 6][1] = ss; }
  __syncthreads();
  if (threadIdx.x == 0) {
    partial[blockIdx.x * 2 + 0] = sm[0][0] + sm[1][0] + sm[2][0] + sm[3][0];
    partial[blockIdx.x * 2 + 1] = sm[0][1] + sm[1][1] + sm[2][1] + sm[3][1];
  }
}

// ---------------------------------------------------------------------------
// BN stats finalize: A = g*rsqrt(var+eps), B = beta - mu*A
// ---------------------------------------------------------------------------
__global__ __launch_bounds__(256) void k_stats(const float* __restrict__ partial,
                                               int nblk, int oc,
                                               const float* __restrict__ g,
                                               const float* __restrict__ beta,
                                               float* __restrict__ ssout) {
  const int o = blockIdx.x;
  float s = 0.f, ss = 0.f;
  for (int b = threadIdx.x; b < nblk; b += 256) {
    s  += partial[b * 2 * oc + o];
    ss += partial[b * 2 * oc + oc + o];
  }
  s = wave_reduce_sum(s);
  ss = wave_reduce_sum(ss);
  __shared__ float sm[4][2];
  if ((threadIdx.x & 63) == 0) { sm[threadIdx.x >> 6][0] = s; sm[threadIdx.x >> 6][1] = ss; }
  __syncthreads();
  if (threadIdx.x == 0) {
    s  = sm[0][0] + sm[1][0] + sm[2][0] + sm[3][0];
    ss = sm[0][1] + sm[1][1] + sm[2][1] + sm[3][1];
    const float count = (float)NS_;
    const float mu = s / count;
    const float var = fmaxf(ss / count - mu * mu, 0.f);
    const float Av = g[o] * rsqrtf(var + 1e-5f);
    ssout[2 * o] = Av;
    ssout[2 * o + 1] = beta[o] - mu * Av;
  }
}

// ---------------------------------------------------------------------------
// final: singleW = sum_e relu(A4*y4+B4); comp = singleW*(sum_e x)/E; dB.
// Per-block max -> pmax[] (NO same-address atomics).
// ---------------------------------------------------------------------------
__global__ __launch_bounds__(256) void k_final(const float* __restrict__ sumI,
                                               const float* __restrict__ sumQ,
                                               const float* __restrict__ y4,
                                               const float* __restrict__ ss4,
                                               float* __restrict__ ydb,
                                               float* __restrict__ pmax) {
  const int w = threadIdx.x >> 6;
  const int lane = threadIdx.x & 63;
  const int p = blockIdx.x * 4 + w;
  const float A = ss4[0], B = ss4[1];
  const size_t base = (size_t)p * E_;

  float sw = fmaxf(0.f, fmaf(A, y4[base + lane], B)) +
             fmaxf(0.f, fmaf(A, y4[base + lane + 64], B));
  sw = wave_reduce_sum(sw);

  __shared__ float s_m[4];
  if (lane == 0) {
    const float ci = sw * sumI[p] * (1.f / (float)E_);
    const float cq = sw * sumQ[p] * (1.f / (float)E_);
    const float mag = sqrtf(ci * ci + cq * cq);
    const float v = 20.f * log10f(mag + 1e-20f);
    ydb[p] = v;
    s_m[w] = v;
  }
  __syncthreads();
  if (threadIdx.x == 0)
    pmax[blockIdx.x] = fmaxf(fmaxf(s_m[0], s_m[1]), fmaxf(s_m[2], s_m[3]));
}

__global__ __launch_bounds__(256) void k_maxred(const float* __restrict__ pmax,
                                                int n, float* __restrict__ gmax) {
  float m = -3.4e38f;
  for (int i = threadIdx.x; i < n; i += 256) m = fmaxf(m, pmax[i]);
  m = wave_reduce_max(m);
  __shared__ float sm[4];
  if ((threadIdx.x & 63) == 0) sm[threadIdx.x >> 6] = m;
  __syncthreads();
  if (threadIdx.x == 0)
    gmax[0] = fmaxf(fmaxf(sm[0], sm[1]), fmaxf(sm[2], sm[3]));
}

__global__ __launch_bounds__(256) void k_sub(const float* __restrict__ ydb,
                                             const float* __restrict__ gmax,
                                             float* __restrict__ out) {
  const int i = blockIdx.x * 256 + threadIdx.x;
  out[i] = ydb[i] - gmax[0];
}

// ---------------------------------------------------------------------------
// Workspace layout (bytes).  Region A is time-multiplexed:
//   x0p (27MB, dead after conv1) -> buf2 (67MB, dead after conv3)
//   -> y4 (16.8MB) + ydb + pmax.
// ---------------------------------------------------------------------------
static constexpr size_t OFF_A     = 0;            // 67,108,864 region
static constexpr size_t OFF_Y4    = 0;            // f32 [NS]   (in A)
static constexpr size_t OFF_YDB   = 16777216;     // f32 [NPIX] (in A)
static constexpr size_t OFF_PMAX  = 16908288;     // f32 [8192] (in A)
static constexpr size_t OFF_BUF1  = 67108864;     // 67,108,864
static constexpr size_t OFF_SUMI  = 134217728;    // 131,072
static constexpr size_t OFF_SUMQ  = 134348800;    // 131,072
static constexpr size_t OFF_PART  = 134479872;    // 262,144
static constexpr size_t OFF_PMSQ  = 134742016;    // 16,384 (4096 f32)
static constexpr size_t OFF_SS    = 134758400;    // 256
static constexpr size_t OFF_MAXSQ = 134758656;    // 4
static constexpr size_t OFF_GMAX  = 134758660;    // 4

extern "C" void kernel_launch(void* const* d_in, const int* in_sizes, int n_in,
                              void* d_out, int out_size, void* d_ws, size_t ws_size,
                              hipStream_t stream) {
  const float* idata     = (const float*)d_in[0];
  const float* qdata     = (const float*)d_in[1];
  const float* angles    = (const float*)d_in[2];
  const float* ele_pos   = (const float*)d_in[3];
  const float* time_zero = (const float*)d_in[4];
  const float* grid      = (const float*)d_in[5];
  const float* w1 = (const float*)d_in[6];  const float* b1 = (const float*)d_in[7];
  const float* g1 = (const float*)d_in[8];  const float* be1 = (const float*)d_in[9];
  const float* w2 = (const float*)d_in[10]; const float* b2 = (const float*)d_in[11];
  const float* g2 = (const float*)d_in[12]; const float* be2 = (const float*)d_in[13];
  const float* w3 = (const float*)d_in[14]; const float* b3 = (const float*)d_in[15];
  const float* g3 = (const float*)d_in[16]; const float* be3 = (const float*)d_in[17];
  const float* w4 = (const float*)d_in[18]; const float* b4 = (const float*)d_in[19];
  const float* g4 = (const float*)d_in[20]; const float* be4 = (const float*)d_in[21];

  char* ws = (char*)d_ws;
  unsigned*     x0p   = (unsigned*)(ws + OFF_A);       // [p][208] bf16-pairs
  uint4*        buf2  = (uint4*)(ws + OFF_A);          // [p][128] units
  float*        y4    = (float*)(ws + OFF_Y4);
  float*        ydb   = (float*)(ws + OFF_YDB);
  float*        pmax  = (float*)(ws + OFF_PMAX);
  uint4*        buf1  = (uint4*)(ws + OFF_BUF1);
  float*        sumI  = (float*)(ws + OFF_SUMI);
  float*        sumQ  = (float*)(ws + OFF_SUMQ);
  float*        part  = (float*)(ws + OFF_PART);
  float*        pmsq  = (float*)(ws + OFF_PMSQ);
  float*        ssAB  = (float*)(ws + OFF_SS);
  float*        maxsq = (float*)(ws + OFF_MAXSQ);
  float*        gmax  = (float*)(ws + OFF_GMAX);

  k_init<<<4096, 256, 0, stream>>>((uint4*)x0p, (const float4*)idata,
                                   (const float4*)qdata, pmsq);
  k_nrmred<<<1, 256, 0, stream>>>(pmsq, maxsq);
  k_beamform<<<NPIX / 2, 256, 0, stream>>>(idata, qdata, angles, ele_pos,
                                           time_zero, grid, maxsq, x0p, sumI, sumQ);

  k_conv1<<<2048, 256, 0, stream>>>(x0p, w1, b1, (uint2*)buf1, part);
  k_stats<<<8, 256, 0, stream>>>(part, 2048, 8, g1, be1, ssAB + 0);

  k_conv23<<<2048, 256, 0, stream>>>(buf1, w2, b2, ssAB + 0, (uint2*)buf2, part);
  k_stats<<<8, 256, 0, stream>>>(part, 2048, 8, g2, be2, ssAB + 16);

  k_conv23<<<2048, 256, 0, stream>>>(buf2, w3, b3, ssAB + 16, (uint2*)buf1, part);
  k_stats<<<8, 256, 0, stream>>>(part, 2048, 8, g3, be3, ssAB + 32);

  k_conv4<<<NS_ / 256, 256, 0, stream>>>(buf1, ssAB + 32, w4, b4, y4, part);
  k_stats<<<1, 256, 0, stream>>>(part, NS_ / 256, 1, g4, be4, ssAB + 48);

  k_final<<<NPIX / 4, 256, 0, stream>>>(sumI, sumQ, y4, ssAB + 48, ydb, pmax);
  k_maxred<<<1, 256, 0, stream>>>(pmax, NPIX / 4, gmax);
  k_sub<<<NPIX / 256, 256, 0, stream>>>(ydb, gmax, (float*)d_out);
}

// Round 9
// 326.646 us; speedup vs baseline: 1.4025x; 1.0240x over previous
//
#include <hip/hip_runtime.h>
#include <hip/hip_bf16.h>

// ---------------------------------------------------------------------------
// Task1_bf_final_CSW2D round 9: e-major beamform with LDS-staged signal.
// R8 counters: k_beamform 45us, VALUBusy 42%, HBM 6.8% -> L2-gather-bound
// (16.7M scattered dword gathers ~ 1GB L2 traffic).  Now: block = (element,
// 1024-pixel chunk); stage the element's whole I/Q signal into LDS (16KB,
// float2-interleaved -> gather = one ds_read_b64 per tap); apod params
// wave-uniform.  sumI/sumQ moved to k_esum (coalesced x0p read, bf16 path
// as in R4/R5).  y4 -> bf16.  k_maxred folded into k_sub.
// ---------------------------------------------------------------------------

#define E_    128
#define NPIX  32768
#define NS_   (NPIX * E_)
#define NSAMP 2048

static constexpr double PI_D     = 3.14159265358979323846;
static constexpr double FS_D     = 20832000.0;
static constexpr double FDEMOD_D = 5208000.0;
static constexpr double C_D      = 1540.0;

typedef __attribute__((ext_vector_type(8))) short short8;
typedef __attribute__((ext_vector_type(4))) float f32x4;

union U8 { uint4 u4; unsigned u32[4]; unsigned short us[8]; short8 s8; };

__device__ __forceinline__ unsigned short f2bf(float f) {
  unsigned u = __float_as_uint(f);
  unsigned r = (u + 0x7fffu + ((u >> 16) & 1u)) >> 16;
  return (unsigned short)r;
}
__device__ __forceinline__ float bflo(unsigned w) { return __uint_as_float(w << 16); }
__device__ __forceinline__ float bfhi(unsigned w) { return __uint_as_float(w & 0xFFFF0000u); }
__device__ __forceinline__ float bf2f(unsigned short s) {
  return __uint_as_float((unsigned)s << 16);
}

__device__ __forceinline__ float wave_reduce_sum(float v) {
  #pragma unroll
  for (int off = 32; off; off >>= 1) v += __shfl_xor(v, off);
  return v;
}
__device__ __forceinline__ float wave_reduce_max(float v) {
  #pragma unroll
  for (int off = 32; off; off >>= 1) v = fmaxf(v, __shfl_xor(v, off));
  return v;
}

// BN+relu one 16B unit (8 channels of one e), repack to bf16
__device__ __forceinline__ uint4 bn_unit(uint4 v, const float* A, const float* B) {
  U8 in; in.u4 = v;
  U8 out;
  #pragma unroll
  for (int w = 0; w < 4; ++w) {
    const unsigned wd = in.u32[w];
    const float yl = fmaxf(0.f, fmaf(A[2 * w], bflo(wd), B[2 * w]));
    const float yh = fmaxf(0.f, fmaf(A[2 * w + 1], bfhi(wd), B[2 * w + 1]));
    out.us[2 * w] = f2bf(yl);
    out.us[2 * w + 1] = f2bf(yh);
  }
  return out.u4;
}

// ---------------------------------------------------------------------------
// init: zero x0p halos + PER-BLOCK max of i^2+q^2 (float4, no atomics)
// ---------------------------------------------------------------------------
__global__ __launch_bounds__(256) void k_init(uint4* __restrict__ x0p,
                                              const float4* __restrict__ id4,
                                              const float4* __restrict__ qd4,
                                              float* __restrict__ pmaxsq) {
  const int idx = blockIdx.x * 256 + threadIdx.x;
  const int row = idx >> 5, k = idx & 31;
  if (k < 20) {
    const int q = (k < 8) ? k : (40 + (k - 8));   // uint4 0..7 and 40..51
    x0p[(size_t)row * 52 + q] = make_uint4(0, 0, 0, 0);
  }
  const float4 iv = id4[idx];
  const float4 qv = qd4[idx];
  float m = fmaxf(fmaxf(iv.x * iv.x + qv.x * qv.x, iv.y * iv.y + qv.y * qv.y),
                  fmaxf(iv.z * iv.z + qv.z * qv.z, iv.w * iv.w + qv.w * qv.w));
  m = wave_reduce_max(m);
  __shared__ float sm[4];
  if ((threadIdx.x & 63) == 0) sm[threadIdx.x >> 6] = m;
  __syncthreads();
  if (threadIdx.x == 0)
    pmaxsq[blockIdx.x] = fmaxf(fmaxf(sm[0], sm[1]), fmaxf(sm[2], sm[3]));
}

__global__ __launch_bounds__(256) void k_nrmred(const float* __restrict__ pmaxsq,
                                                float* __restrict__ maxsq) {
  float m = 0.f;
  for (int i = threadIdx.x; i < 4096; i += 256) m = fmaxf(m, pmaxsq[i]);
  m = wave_reduce_max(m);
  __shared__ float sm[4];
  if ((threadIdx.x & 63) == 0) sm[threadIdx.x >> 6] = m;
  __syncthreads();
  if (threadIdx.x == 0)
    maxsq[0] = fmaxf(fmaxf(sm[0], sm[1]), fmaxf(sm[2], sm[3]));
}

// ---------------------------------------------------------------------------
// beamform, e-major: block = (element e, 1024-pixel chunk).  Signal for e is
// staged once into LDS as interleaved (I,Q) float2 -> each tap gather is one
// ds_read_b64.  blockIdx = chunk*128 + e so the 128 e-blocks of one chunk
// are dispatched together (their x0p writes share L2 lines).
// ---------------------------------------------------------------------------
__global__ __launch_bounds__(256) void k_beamform(
    const float4* __restrict__ id4, const float4* __restrict__ qd4,
    const float* __restrict__ angles, const float* __restrict__ ele_pos,
    const float* __restrict__ time_zero, const float* __restrict__ grid,
    const float* __restrict__ maxsq, unsigned* __restrict__ x0p) {
  __shared__ float2 sig[NSAMP];          // 16 KB
  const int e = blockIdx.x & 127;
  const int chunk = blockIdx.x >> 7;     // 0..31

  const float4* irow = id4 + e * (NSAMP / 4);
  const float4* qrow = qd4 + e * (NSAMP / 4);
  #pragma unroll
  for (int k0 = 0; k0 < 2; ++k0) {
    const int k = k0 * 256 + threadIdx.x;
    const float4 iv = irow[k];
    const float4 qv = qrow[k];
    sig[4 * k + 0] = make_float2(iv.x, qv.x);
    sig[4 * k + 1] = make_float2(iv.y, qv.y);
    sig[4 * k + 2] = make_float2(iv.z, qv.z);
    sig[4 * k + 3] = make_float2(iv.w, qv.w);
  }
  __syncthreads();

  const float inv = 1.0f / sqrtf(*maxsq);
  const float ang = angles[0];
  const float tz  = time_zero[0];

  constexpr float SC    = (float)(FS_D / C_D);
  constexpr float TH2R  = (float)(2.0 * FDEMOD_D / C_D);
  constexpr float TWOPI = (float)(2.0 * PI_D);

  const float sa = __sinf(ang);
  const float ca = __cosf(ang);
  const float ta = sa / ca;
  const float ex  = ele_pos[e * 3];
  const float ex0 = ele_pos[0];
  const float exl = ele_pos[127 * 3];

  #pragma unroll
  for (int s = 0; s < 4; ++s) {
    const int p = chunk * 1024 + s * 256 + threadIdx.x;
    const float px = grid[p * 3 + 0];
    const float pz = grid[p * 3 + 2];

    const float txdel = (px * sa + pz * ca + tz * (float)C_D) * SC;
    const float dx = px - ex;
    const float rxdel = sqrtf(dx * dx + pz * pz) * SC;

    const float delays = txdel + rxdel;
    const float d0 = floorf(delays);
    const float frac = delays - d0;
    const int i0 = (int)d0;

    const int c0 = min(max(i0, 0), NSAMP - 1);
    const int c1 = min(max(i0 + 1, 0), NSAMP - 1);
    const float2 s0 = sig[c0];
    const float2 s1 = sig[c1];
    const bool m0 = (i0 >= 0) && (i0 < NSAMP);
    const bool m1 = (i0 + 1 >= 0) && (i0 + 1 < NSAMP);
    const float iv0 = m0 ? s0.x : 0.f;
    const float qv0 = m0 ? s0.y : 0.f;
    const float iv1 = m1 ? s1.x : 0.f;
    const float qv1 = m1 ? s1.y : 0.f;
    const float ifoc = (iv0 * (1.f - frac) + iv1 * frac) * inv;
    const float qfoc = (qv0 * (1.f - frac) + qv1 * frac) * inv;

    // theta/2pi = delays*0.25 - pz*TH2R  (exact: FS = 4*FDEMOD)
    const float trev = fmaf(delays, 0.25f, -pz * TH2R);
    const float fr = trev - floorf(trev);
    const float st = __sinf(fr * TWOPI);
    const float ct = __cosf(fr * TWOPI);
    const float ir = ifoc * ct - qfoc * st;
    const float qr = qfoc * ct + ifoc * st;

    const float avx = fabsf(dx);
    const bool mrx = (fabsf(pz) > avx) || (avx <= 0.001f) ||
                     ((dx >= 0.001f) && (px <= ex0)) ||
                     ((dx <= -0.001f) && (px >= exl));
    const float xproj = px - pz * ta;
    const bool mtx = (xproj >= ex0 * 1.2f) && (xproj <= exl * 1.2f);
    const float a = (mrx && mtx) ? 1.f : 0.f;

    x0p[(size_t)p * 208 + 32 + e] =
        (unsigned)f2bf(ir * a) | ((unsigned)f2bf(qr * a) << 16);
  }
}

// ---------------------------------------------------------------------------
// per-pixel sums over e from x0p (coalesced; bf16-rounded inputs — the
// R4/R5-proven path, absmax 2.0 vs threshold 8.28)
// ---------------------------------------------------------------------------
__global__ __launch_bounds__(256) void k_esum(const unsigned* __restrict__ x0p,
                                              float* __restrict__ sumI,
                                              float* __restrict__ sumQ) {
  const int w = threadIdx.x >> 6;
  const int lane = threadIdx.x & 63;
  const int p = blockIdx.x * 4 + w;
  const unsigned* row = x0p + (size_t)p * 208 + 32;
  const unsigned v0 = row[lane];
  const unsigned v1 = row[lane + 64];
  float si = bflo(v0) + bflo(v1);
  float sq = bfhi(v0) + bfhi(v1);
  si = wave_reduce_sum(si);
  sq = wave_reduce_sum(sq);
  if (lane == 0) { sumI[p] = si; sumQ[p] = sq; }
}

// ---------------------------------------------------------------------------
// conv1: IC=2, K=65, pad=32, OC=8.  MFMA, taps padded to 80 (5 mfma / tile).
// B fragment = ONE contiguous uint4 (4B-aligned dwordx4 fine on gfx950).
// Output: compact [p][128][8ch] (16B per e).
// ---------------------------------------------------------------------------
__global__ __launch_bounds__(256) void k_conv1(
    const unsigned* __restrict__ x0p, const float* __restrict__ wgt,
    const float* __restrict__ bias, uint2* __restrict__ outp,
    float* __restrict__ partial) {
  const int tid = threadIdx.x;
  const int lane = tid & 63;
  const int wv = tid >> 6;
  const int gw = blockIdx.x * 4 + wv;         // 8192 waves
  const int n = lane & 15, kq = lane >> 4;

  short8 af[5];
  #pragma unroll
  for (int m = 0; m < 5; ++m) {
    U8 u;
    #pragma unroll
    for (int j = 0; j < 8; ++j) {
      const int tap = m * 16 + kq * 4 + (j >> 1);
      const int i = j & 1;
      const float w = (n < 8 && tap < 65) ? wgt[(n * 2 + i) * 65 + tap] : 0.f;
      u.us[j] = f2bf(w);
    }
    af[m] = u.s8;
  }
  float bias_r[4];
  #pragma unroll
  for (int r = 0; r < 4; ++r) {
    const int oo = kq * 4 + r;
    bias_r[r] = (oo < 8) ? bias[oo] : 0.f;
  }

  float sum[4] = {0, 0, 0, 0}, ssq[4] = {0, 0, 0, 0};

  for (int p = gw; p < NPIX; p += 8192) {
    const unsigned* row = x0p + (size_t)p * 208;
    uint2* orow = outp + (size_t)p * 256;
    for (int t = 0; t < 8; ++t) {
      f32x4 acc = {bias_r[0], bias_r[1], bias_r[2], bias_r[3]};
      const int base = t * 16 + n + kq * 4;
      #pragma unroll
      for (int m = 0; m < 5; ++m) {
        U8 b;
        b.u4 = *(const uint4*)(row + base + m * 16);
        acc = __builtin_amdgcn_mfma_f32_16x16x32_bf16(af[m], b.s8, acc, 0, 0, 0);
      }
      if (lane < 32) {
        const unsigned lo = (unsigned)f2bf(acc[0]) | ((unsigned)f2bf(acc[1]) << 16);
        const unsigned hi = (unsigned)f2bf(acc[2]) | ((unsigned)f2bf(acc[3]) << 16);
        orow[(t * 16 + n) * 2 + kq] = make_uint2(lo, hi);
        #pragma unroll
        for (int r = 0; r < 4; ++r) { const float v = acc[r]; sum[r] += v; ssq[r] += v * v; }
      }
    }
  }

  #pragma unroll
  for (int off = 1; off <= 8; off <<= 1)
    #pragma unroll
    for (int r = 0; r < 4; ++r) { sum[r] += __shfl_xor(sum[r], off); ssq[r] += __shfl_xor(ssq[r], off); }
  __shared__ float s_red[4][16];
  if (lane == 0)
    #pragma unroll
    for (int r = 0; r < 4; ++r) { s_red[wv][r] = sum[r]; s_red[wv][8 + r] = ssq[r]; }
  if (lane == 16)
    #pragma unroll
    for (int r = 0; r < 4; ++r) { s_red[wv][4 + r] = sum[r]; s_red[wv][12 + r] = ssq[r]; }
  __syncthreads();
  if (tid < 16)
    partial[blockIdx.x * 16 + tid] =
        s_red[0][tid] + s_red[1][tid] + s_red[2][tid] + s_red[3][tid];
}

// ---------------------------------------------------------------------------
// conv2/3: IC=8, K=15, pad=7, OC=8.  Per-wave PRIVATE LDS row staging (no
// intra-loop barriers).  BN+relu once per element; halos zeroed (pad AFTER
// BN+relu).  Fragments: ds_read_b128.
// ---------------------------------------------------------------------------
__global__ __launch_bounds__(256) void k_conv23(
    const uint4* __restrict__ inp, const float* __restrict__ wgt,
    const float* __restrict__ bias, const float* __restrict__ bnAB,
    uint2* __restrict__ outp, float* __restrict__ partial) {
  __shared__ uint4 s_row[4][144];
  const int tid = threadIdx.x;
  const int lane = tid & 63;
  const int wv = tid >> 6;
  const int gw = blockIdx.x * 4 + wv;
  const int n = lane & 15, kq = lane >> 4;

  float A[8], Bc[8];
  #pragma unroll
  for (int i = 0; i < 8; ++i) { A[i] = bnAB[2 * i]; Bc[i] = bnAB[2 * i + 1]; }

  short8 af[4];
  #pragma unroll
  for (int m = 0; m < 4; ++m) {
    U8 u;
    #pragma unroll
    for (int j = 0; j < 8; ++j) {
      const int tap = m * 4 + kq;
      const float w = (n < 8 && tap < 15) ? wgt[(n * 8 + j) * 15 + tap] : 0.f;
      u.us[j] = f2bf(w);
    }
    af[m] = u.s8;
  }
  float bias_r[4];
  #pragma unroll
  for (int r = 0; r < 4; ++r) {
    const int oo = kq * 4 + r;
    bias_r[r] = (oo < 8) ? bias[oo] : 0.f;
  }

  uint4* lds = s_row[wv];
  if (lane < 7)  lds[lane] = make_uint4(0, 0, 0, 0);
  if (lane >= 7 && lane < 16) lds[128 + lane] = make_uint4(0, 0, 0, 0);

  float sum[4] = {0, 0, 0, 0}, ssq[4] = {0, 0, 0, 0};

  for (int p = gw; p < NPIX; p += 8192) {
    const uint4* grow = inp + (size_t)p * 128;
    const uint4 v0 = grow[lane];
    const uint4 v1 = grow[64 + lane];
    lds[7 + lane]  = bn_unit(v0, A, Bc);
    lds[71 + lane] = bn_unit(v1, A, Bc);

    uint2* orow = outp + (size_t)p * 256;
    for (int t = 0; t < 8; ++t) {
      f32x4 acc = {bias_r[0], bias_r[1], bias_r[2], bias_r[3]};
      const int base = t * 16 + n + kq;
      #pragma unroll
      for (int m = 0; m < 4; ++m) {
        U8 b;
        b.u4 = lds[base + m * 4];
        acc = __builtin_amdgcn_mfma_f32_16x16x32_bf16(af[m], b.s8, acc, 0, 0, 0);
      }
      if (lane < 32) {
        const unsigned lo = (unsigned)f2bf(acc[0]) | ((unsigned)f2bf(acc[1]) << 16);
        const unsigned hi = (unsigned)f2bf(acc[2]) | ((unsigned)f2bf(acc[3]) << 16);
        orow[(t * 16 + n) * 2 + kq] = make_uint2(lo, hi);
        #pragma unroll
        for (int r = 0; r < 4; ++r) { const float v = acc[r]; sum[r] += v; ssq[r] += v * v; }
      }
    }
  }

  #pragma unroll
  for (int off = 1; off <= 8; off <<= 1)
    #pragma unroll
    for (int r = 0; r < 4; ++r) { sum[r] += __shfl_xor(sum[r], off); ssq[r] += __shfl_xor(ssq[r], off); }
  __shared__ float s_red[4][16];
  if (lane == 0)
    #pragma unroll
    for (int r = 0; r < 4; ++r) { s_red[wv][r] = sum[r]; s_red[wv][8 + r] = ssq[r]; }
  if (lane == 16)
    #pragma unroll
    for (int r = 0; r < 4; ++r) { s_red[wv][4 + r] = sum[r]; s_red[wv][12 + r] = ssq[r]; }
  __syncthreads();
  if (tid < 16)
    partial[blockIdx.x * 16 + tid] =
        s_red[0][tid] + s_red[1][tid] + s_red[2][tid] + s_red[3][tid];
}

// ---------------------------------------------------------------------------
// conv4: IC=8, K=3, pad=1, OC=1.  VALU; BN3+relu fused on load; pad taps
// contribute exactly 0.  Output bf16 (ushort).
// ---------------------------------------------------------------------------
__global__ __launch_bounds__(256) void k_conv4(
    const uint4* __restrict__ inp, const float* __restrict__ bnAB,
    const float* __restrict__ w4, const float* __restrict__ b4,
    unsigned short* __restrict__ y4b, float* __restrict__ partial) {
  const int idx = blockIdx.x * 256 + threadIdx.x;
  const int p = idx >> 7, e = idx & 127;

  float A[8], Bc[8];
  #pragma unroll
  for (int i = 0; i < 8; ++i) { A[i] = bnAB[2 * i]; Bc[i] = bnAB[2 * i + 1]; }

  float acc = b4[0];
  const uint4* row = inp + (size_t)p * 128 + e;
  #pragma unroll
  for (int kt = 0; kt < 3; ++kt) {
    const int ee = e + kt - 1;
    if (ee >= 0 && ee < E_) {
      U8 u; u.u4 = row[kt - 1];
      #pragma unroll
      for (int i = 0; i < 8; ++i) {
        const unsigned wd = u.u32[i >> 1];
        const float x = (i & 1) ? bfhi(wd) : bflo(wd);
        const float v = fmaxf(0.f, fmaf(A[i], x, Bc[i]));
        acc = fmaf(w4[i * 3 + kt], v, acc);
      }
    }
  }
  y4b[idx] = f2bf(acc);

  float s = wave_reduce_sum(acc);
  float ss = wave_reduce_sum(acc * acc);
  __shared__ float sm[4][2];
  if ((threadIdx.x & 63) == 0) { sm[threadIdx.x >> 6][0] = s; sm[threadIdx.x >> 6][1] = ss; }
  __syncthreads();
  if (threadIdx.x == 0) {
    partial[blockIdx.x * 2 + 0] = sm[0][0] + sm[1][0] + sm[2][0] + sm[3][0];
    partial[blockIdx.x * 2 + 1] = sm[0][1] + sm[1][1] + sm[2][1] + sm[3][1];
  }
}

// ---------------------------------------------------------------------------
// BN stats finalize: A = g*rsqrt(var+eps), B = beta - mu*A
// ---------------------------------------------------------------------------
__global__ __launch_bounds__(256) void k_stats(const float* __restrict__ partial,
                                               int nblk, int oc,
                                               const float* __restrict__ g,
                                               const float* __restrict__ beta,
                                               float* __restrict__ ssout) {
  const int o = blockIdx.x;
  float s = 0.f, ss = 0.f;
  for (int b = threadIdx.x; b < nblk; b += 256) {
    s  += partial[b * 2 * oc + o];
    ss += partial[b * 2 * oc + oc + o];
  }
  s = wave_reduce_sum(s);
  ss = wave_reduce_sum(ss);
  __shared__ float sm[4][2];
  if ((threadIdx.x & 63) == 0) { sm[threadIdx.x >> 6][0] = s; sm[threadIdx.x >> 6][1] = ss; }
  __syncthreads();
  if (threadIdx.x == 0) {
    s  = sm[0][0] + sm[1][0] + sm[2][0] + sm[3][0];
    ss = sm[0][1] + sm[1][1] + sm[2][1] + sm[3][1];
    const float count = (float)NS_;
    const float mu = s / count;
    const float var = fmaxf(ss / count - mu * mu, 0.f);
    const float Av = g[o] * rsqrtf(var + 1e-5f);
    ssout[2 * o] = Av;
    ssout[2 * o + 1] = beta[o] - mu * Av;
  }
}

// ---------------------------------------------------------------------------
// final: singleW = sum_e relu(A4*y4+B4); comp = singleW*(sum_e x)/E; dB.
// Per-block max -> pmax[] (no same-address atomics).
// ---------------------------------------------------------------------------
__global__ __launch_bounds__(256) void k_final(const float* __restrict__ sumI,
                                               const float* __restrict__ sumQ,
                                               const unsigned short* __restrict__ y4b,
                                               const float* __restrict__ ss4,
                                               float* __restrict__ ydb,
                                               float* __restrict__ pmax) {
  const int w = threadIdx.x >> 6;
  const int lane = threadIdx.x & 63;
  const int p = blockIdx.x * 4 + w;
  const float A = ss4[0], B = ss4[1];
  const size_t base = (size_t)p * E_;

  float sw = fmaxf(0.f, fmaf(A, bf2f(y4b[base + lane]), B)) +
             fmaxf(0.f, fmaf(A, bf2f(y4b[base + lane + 64]), B));
  sw = wave_reduce_sum(sw);

  __shared__ float s_m[4];
  if (lane == 0) {
    const float ci = sw * sumI[p] * (1.f / (float)E_);
    const float cq = sw * sumQ[p] * (1.f / (float)E_);
    const float mag = sqrtf(ci * ci + cq * cq);
    const float v = 20.f * log10f(mag + 1e-20f);
    ydb[p] = v;
    s_m[w] = v;
  }
  __syncthreads();
  if (threadIdx.x == 0)
    pmax[blockIdx.x] = fmaxf(fmaxf(s_m[0], s_m[1]), fmaxf(s_m[2], s_m[3]));
}

// k_sub with inline global-max: each block re-reduces pmax[8192] (32KB L2
// reads/block — cheaper than a separate launch + dependency).
__global__ __launch_bounds__(256) void k_sub(const float* __restrict__ ydb,
                                             const float* __restrict__ pmax,
                                             float* __restrict__ out) {
  float m = -3.4e38f;
  for (int i = threadIdx.x; i < NPIX / 4; i += 256) m = fmaxf(m, pmax[i]);
  m = wave_reduce_max(m);
  __shared__ float sm[4];
  if ((threadIdx.x & 63) == 0) sm[threadIdx.x >> 6] = m;
  __syncthreads();
  __shared__ float sgm;
  if (threadIdx.x == 0)
    sgm = fmaxf(fmaxf(sm[0], sm[1]), fmaxf(sm[2], sm[3]));
  __syncthreads();
  const int i = blockIdx.x * 256 + threadIdx.x;
  out[i] = ydb[i] - sgm;
}

// ---------------------------------------------------------------------------
// Workspace layout (bytes).  Region A is time-multiplexed:
//   x0p (27MB, dead after conv2-start... kept through k_esum+conv1) ->
//   buf2 (67MB, dead after conv3) -> y4b (8.4MB) + ydb + pmax.
// ---------------------------------------------------------------------------
static constexpr size_t OFF_A     = 0;            // 67,108,864 region
static constexpr size_t OFF_Y4    = 0;            // bf16 [NS]  (in A)
static constexpr size_t OFF_YDB   = 16777216;     // f32 [NPIX] (in A)
static constexpr size_t OFF_PMAX  = 16908288;     // f32 [8192] (in A)
static constexpr size_t OFF_BUF1  = 67108864;     // 67,108,864
static constexpr size_t OFF_SUMI  = 134217728;    // 131,072
static constexpr size_t OFF_SUMQ  = 134348800;    // 131,072
static constexpr size_t OFF_PART  = 134479872;    // 262,144
static constexpr size_t OFF_PMSQ  = 134742016;    // 16,384 (4096 f32)
static constexpr size_t OFF_SS    = 134758400;    // 256
static constexpr size_t OFF_MAXSQ = 134758656;    // 4
static constexpr size_t OFF_GMAX  = 134758660;    // 4

extern "C" void kernel_launch(void* const* d_in, const int* in_sizes, int n_in,
                              void* d_out, int out_size, void* d_ws, size_t ws_size,
                              hipStream_t stream) {
  const float* idata     = (const float*)d_in[0];
  const float* qdata     = (const float*)d_in[1];
  const float* angles    = (const float*)d_in[2];
  const float* ele_pos   = (const float*)d_in[3];
  const float* time_zero = (const float*)d_in[4];
  const float* grid      = (const float*)d_in[5];
  const float* w1 = (const float*)d_in[6];  const float* b1 = (const float*)d_in[7];
  const float* g1 = (const float*)d_in[8];  const float* be1 = (const float*)d_in[9];
  const float* w2 = (const float*)d_in[10]; const float* b2 = (const float*)d_in[11];
  const float* g2 = (const float*)d_in[12]; const float* be2 = (const float*)d_in[13];
  const float* w3 = (const float*)d_in[14]; const float* b3 = (const float*)d_in[15];
  const float* g3 = (const float*)d_in[16]; const float* be3 = (const float*)d_in[17];
  const float* w4 = (const float*)d_in[18]; const float* b4 = (const float*)d_in[19];
  const float* g4 = (const float*)d_in[20]; const float* be4 = (const float*)d_in[21];

  char* ws = (char*)d_ws;
  unsigned*       x0p   = (unsigned*)(ws + OFF_A);       // [p][208] bf16-pairs
  uint4*          buf2  = (uint4*)(ws + OFF_A);          // [p][128] units
  unsigned short* y4b   = (unsigned short*)(ws + OFF_Y4);
  float*          ydb   = (float*)(ws + OFF_YDB);
  float*          pmax  = (float*)(ws + OFF_PMAX);
  uint4*          buf1  = (uint4*)(ws + OFF_BUF1);
  float*          sumI  = (float*)(ws + OFF_SUMI);
  float*          sumQ  = (float*)(ws + OFF_SUMQ);
  float*          part  = (float*)(ws + OFF_PART);
  float*          pmsq  = (float*)(ws + OFF_PMSQ);
  float*          ssAB  = (float*)(ws + OFF_SS);
  float*          maxsq = (float*)(ws + OFF_MAXSQ);

  k_init<<<4096, 256, 0, stream>>>((uint4*)x0p, (const float4*)idata,
                                   (const float4*)qdata, pmsq);
  k_nrmred<<<1, 256, 0, stream>>>(pmsq, maxsq);
  k_beamform<<<4096, 256, 0, stream>>>((const float4*)idata, (const float4*)qdata,
                                       angles, ele_pos, time_zero, grid,
                                       maxsq, x0p);
  k_esum<<<NPIX / 4, 256, 0, stream>>>(x0p, sumI, sumQ);

  k_conv1<<<2048, 256, 0, stream>>>(x0p, w1, b1, (uint2*)buf1, part);
  k_stats<<<8, 256, 0, stream>>>(part, 2048, 8, g1, be1, ssAB + 0);

  k_conv23<<<2048, 256, 0, stream>>>(buf1, w2, b2, ssAB + 0, (uint2*)buf2, part);
  k_stats<<<8, 256, 0, stream>>>(part, 2048, 8, g2, be2, ssAB + 16);

  k_conv23<<<2048, 256, 0, stream>>>(buf2, w3, b3, ssAB + 16, (uint2*)buf1, part);
  k_stats<<<8, 256, 0, stream>>>(part, 2048, 8, g3, be3, ssAB + 32);

  k_conv4<<<NS_ / 256, 256, 0, stream>>>(buf1, ssAB + 32, w4, b4, y4b, part);
  k_stats<<<1, 256, 0, stream>>>(part, NS_ / 256, 1, g4, be4, ssAB + 48);

  k_final<<<NPIX / 4, 256, 0, stream>>>(sumI, sumQ, y4b, ssAB + 48, ydb, pmax);
  k_sub<<<NPIX / 256, 256, 0, stream>>>(ydb, pmax, (float*)d_out);
}

// Round 10
// 322.467 us; speedup vs baseline: 1.4207x; 1.0130x over previous
//
#include <hip/hip_runtime.h>
#include <hip/hip_bf16.h>

// ---------------------------------------------------------------------------
// Task1_bf_final_CSW2D round 10:
//  - conv1: rolling-window fragment registers (12 loads/row instead of 40 —
//    R9 counters showed 48x L1 amplification, MfmaUtil 17.5%/VALUBusy 32%)
//  - k_esum folded into conv1 (wave owns the row anyway)      [-1 launch]
//  - k_nrmred folded into beamform (block self-reduces pmsq)  [-1 launch]
// Everything else identical to R9.
// ---------------------------------------------------------------------------

#define E_    128
#define NPIX  32768
#define NS_   (NPIX * E_)
#define NSAMP 2048

static constexpr double PI_D     = 3.14159265358979323846;
static constexpr double FS_D     = 20832000.0;
static constexpr double FDEMOD_D = 5208000.0;
static constexpr double C_D      = 1540.0;

typedef __attribute__((ext_vector_type(8))) short short8;
typedef __attribute__((ext_vector_type(4))) float f32x4;

union U8 { uint4 u4; unsigned u32[4]; unsigned short us[8]; short8 s8; };

__device__ __forceinline__ unsigned short f2bf(float f) {
  unsigned u = __float_as_uint(f);
  unsigned r = (u + 0x7fffu + ((u >> 16) & 1u)) >> 16;
  return (unsigned short)r;
}
__device__ __forceinline__ float bflo(unsigned w) { return __uint_as_float(w << 16); }
__device__ __forceinline__ float bfhi(unsigned w) { return __uint_as_float(w & 0xFFFF0000u); }
__device__ __forceinline__ float bf2f(unsigned short s) {
  return __uint_as_float((unsigned)s << 16);
}

__device__ __forceinline__ float wave_reduce_sum(float v) {
  #pragma unroll
  for (int off = 32; off; off >>= 1) v += __shfl_xor(v, off);
  return v;
}
__device__ __forceinline__ float wave_reduce_max(float v) {
  #pragma unroll
  for (int off = 32; off; off >>= 1) v = fmaxf(v, __shfl_xor(v, off));
  return v;
}

// BN+relu one 16B unit (8 channels of one e), repack to bf16
__device__ __forceinline__ uint4 bn_unit(uint4 v, const float* A, const float* B) {
  U8 in; in.u4 = v;
  U8 out;
  #pragma unroll
  for (int w = 0; w < 4; ++w) {
    const unsigned wd = in.u32[w];
    const float yl = fmaxf(0.f, fmaf(A[2 * w], bflo(wd), B[2 * w]));
    const float yh = fmaxf(0.f, fmaf(A[2 * w + 1], bfhi(wd), B[2 * w + 1]));
    out.us[2 * w] = f2bf(yl);
    out.us[2 * w + 1] = f2bf(yh);
  }
  return out.u4;
}

// ---------------------------------------------------------------------------
// init: zero x0p halos + PER-BLOCK max of i^2+q^2 (float4, no atomics)
// ---------------------------------------------------------------------------
__global__ __launch_bounds__(256) void k_init(uint4* __restrict__ x0p,
                                              const float4* __restrict__ id4,
                                              const float4* __restrict__ qd4,
                                              float* __restrict__ pmaxsq) {
  const int idx = blockIdx.x * 256 + threadIdx.x;
  const int row = idx >> 5, k = idx & 31;
  if (k < 20) {
    const int q = (k < 8) ? k : (40 + (k - 8));   // uint4 0..7 and 40..51
    x0p[(size_t)row * 52 + q] = make_uint4(0, 0, 0, 0);
  }
  const float4 iv = id4[idx];
  const float4 qv = qd4[idx];
  float m = fmaxf(fmaxf(iv.x * iv.x + qv.x * qv.x, iv.y * iv.y + qv.y * qv.y),
                  fmaxf(iv.z * iv.z + qv.z * qv.z, iv.w * iv.w + qv.w * qv.w));
  m = wave_reduce_max(m);
  __shared__ float sm[4];
  if ((threadIdx.x & 63) == 0) sm[threadIdx.x >> 6] = m;
  __syncthreads();
  if (threadIdx.x == 0)
    pmaxsq[blockIdx.x] = fmaxf(fmaxf(sm[0], sm[1]), fmaxf(sm[2], sm[3]));
}

// ---------------------------------------------------------------------------
// beamform, e-major: block = (element e, 1024-pixel chunk).  Signal staged
// into LDS as (I,Q) float2; each tap gather = one ds_read_b64.  Each block
// self-reduces pmsq[4096] (L2/L3-hot) -> no separate nrmred launch.
// ---------------------------------------------------------------------------
__global__ __launch_bounds__(256) void k_beamform(
    const float4* __restrict__ id4, const float4* __restrict__ qd4,
    const float* __restrict__ angles, const float* __restrict__ ele_pos,
    const float* __restrict__ time_zero, const float* __restrict__ grid,
    const float* __restrict__ pmaxsq, unsigned* __restrict__ x0p) {
  __shared__ float2 sig[NSAMP];          // 16 KB
  __shared__ float smax[4];
  const int e = blockIdx.x & 127;
  const int chunk = blockIdx.x >> 7;     // 0..31

  const float4* irow = id4 + e * (NSAMP / 4);
  const float4* qrow = qd4 + e * (NSAMP / 4);
  #pragma unroll
  for (int k0 = 0; k0 < 2; ++k0) {
    const int k = k0 * 256 + threadIdx.x;
    const float4 iv = irow[k];
    const float4 qv = qrow[k];
    sig[4 * k + 0] = make_float2(iv.x, qv.x);
    sig[4 * k + 1] = make_float2(iv.y, qv.y);
    sig[4 * k + 2] = make_float2(iv.z, qv.z);
    sig[4 * k + 3] = make_float2(iv.w, qv.w);
  }
  // self-reduce the normalization max (16 KB, cached)
  float mx = 0.f;
  for (int i = threadIdx.x; i < 4096; i += 256) mx = fmaxf(mx, pmaxsq[i]);
  mx = wave_reduce_max(mx);
  if ((threadIdx.x & 63) == 0) smax[threadIdx.x >> 6] = mx;
  __syncthreads();
  const float inv =
      1.0f / sqrtf(fmaxf(fmaxf(smax[0], smax[1]), fmaxf(smax[2], smax[3])));

  const float ang = angles[0];
  const float tz  = time_zero[0];

  constexpr float SC    = (float)(FS_D / C_D);
  constexpr float TH2R  = (float)(2.0 * FDEMOD_D / C_D);
  constexpr float TWOPI = (float)(2.0 * PI_D);

  const float sa = __sinf(ang);
  const float ca = __cosf(ang);
  const float ta = sa / ca;
  const float ex  = ele_pos[e * 3];
  const float ex0 = ele_pos[0];
  const float exl = ele_pos[127 * 3];

  #pragma unroll
  for (int s = 0; s < 4; ++s) {
    const int p = chunk * 1024 + s * 256 + threadIdx.x;
    const float px = grid[p * 3 + 0];
    const float pz = grid[p * 3 + 2];

    const float txdel = (px * sa + pz * ca + tz * (float)C_D) * SC;
    const float dx = px - ex;
    const float rxdel = sqrtf(dx * dx + pz * pz) * SC;

    const float delays = txdel + rxdel;
    const float d0 = floorf(delays);
    const float frac = delays - d0;
    const int i0 = (int)d0;

    const int c0 = min(max(i0, 0), NSAMP - 1);
    const int c1 = min(max(i0 + 1, 0), NSAMP - 1);
    const float2 s0 = sig[c0];
    const float2 s1 = sig[c1];
    const bool m0 = (i0 >= 0) && (i0 < NSAMP);
    const bool m1 = (i0 + 1 >= 0) && (i0 + 1 < NSAMP);
    const float iv0 = m0 ? s0.x : 0.f;
    const float qv0 = m0 ? s0.y : 0.f;
    const float iv1 = m1 ? s1.x : 0.f;
    const float qv1 = m1 ? s1.y : 0.f;
    const float ifoc = (iv0 * (1.f - frac) + iv1 * frac) * inv;
    const float qfoc = (qv0 * (1.f - frac) + qv1 * frac) * inv;

    // theta/2pi = delays*0.25 - pz*TH2R  (exact: FS = 4*FDEMOD)
    const float trev = fmaf(delays, 0.25f, -pz * TH2R);
    const float fr = trev - floorf(trev);
    const float st = __sinf(fr * TWOPI);
    const float ct = __cosf(fr * TWOPI);
    const float ir = ifoc * ct - qfoc * st;
    const float qr = qfoc * ct + ifoc * st;

    const float avx = fabsf(dx);
    const bool mrx = (fabsf(pz) > avx) || (avx <= 0.001f) ||
                     ((dx >= 0.001f) && (px <= ex0)) ||
                     ((dx <= -0.001f) && (px >= exl));
    const float xproj = px - pz * ta;
    const bool mtx = (xproj >= ex0 * 1.2f) && (xproj <= exl * 1.2f);
    const float a = (mrx && mtx) ? 1.f : 0.f;

    x0p[(size_t)p * 208 + 32 + e] =
        (unsigned)f2bf(ir * a) | ((unsigned)f2bf(qr * a) << 16);
  }
}

// ---------------------------------------------------------------------------
// conv1: IC=2, K=65, pad=32, OC=8.  MFMA, taps padded to 80 (5 mfma / tile).
// Rolling-window fragments: windows w=0..11 at slot n+kq*4+16w; tile t uses
// w=t..t+4 (A's m = w-t).  12 loads/row instead of 40 (3.3x less L1
// traffic).  Also emits per-row e-sums (folded k_esum).
// Output: compact [p][128][8ch] (16B per e).
// ---------------------------------------------------------------------------
__global__ __launch_bounds__(256) void k_conv1(
    const unsigned* __restrict__ x0p, const float* __restrict__ wgt,
    const float* __restrict__ bias, uint2* __restrict__ outp,
    float* __restrict__ partial,
    float* __restrict__ sumI, float* __restrict__ sumQ) {
  const int tid = threadIdx.x;
  const int lane = tid & 63;
  const int wv = tid >> 6;
  const int gw = blockIdx.x * 4 + wv;         // 8192 waves
  const int n = lane & 15, kq = lane >> 4;

  short8 af[5];
  #pragma unroll
  for (int m = 0; m < 5; ++m) {
    U8 u;
    #pragma unroll
    for (int j = 0; j < 8; ++j) {
      const int tap = m * 16 + kq * 4 + (j >> 1);
      const int i = j & 1;
      const float w = (n < 8 && tap < 65) ? wgt[(n * 2 + i) * 65 + tap] : 0.f;
      u.us[j] = f2bf(w);
    }
    af[m] = u.s8;
  }
  float bias_r[4];
  #pragma unroll
  for (int r = 0; r < 4; ++r) {
    const int oo = kq * 4 + r;
    bias_r[r] = (oo < 8) ? bias[oo] : 0.f;
  }

  float sum[4] = {0, 0, 0, 0}, ssq[4] = {0, 0, 0, 0};

  for (int p = gw; p < NPIX; p += 8192) {
    const unsigned* row = x0p + (size_t)p * 208;
    uint2* orow = outp + (size_t)p * 256;
    const int sbase = n + kq * 4;

    // e-sums for k_final (folded k_esum; bf16 inputs, same order as before)
    {
      const unsigned v0 = row[32 + lane];
      const unsigned v1 = row[96 + lane];
      float si = bflo(v0) + bflo(v1);
      float sq = bfhi(v0) + bfhi(v1);
      si = wave_reduce_sum(si);
      sq = wave_reduce_sum(sq);
      if (lane == 0) { sumI[p] = si; sumQ[p] = sq; }
    }

    U8 f[5];
    #pragma unroll
    for (int j = 0; j < 5; ++j)
      f[j].u4 = *(const uint4*)(row + sbase + 16 * j);

    #pragma unroll
    for (int t = 0; t < 8; ++t) {
      f32x4 acc = {bias_r[0], bias_r[1], bias_r[2], bias_r[3]};
      #pragma unroll
      for (int m = 0; m < 5; ++m)
        acc = __builtin_amdgcn_mfma_f32_16x16x32_bf16(af[m], f[m].s8, acc, 0, 0, 0);

      if (lane < 32) {
        const unsigned lo = (unsigned)f2bf(acc[0]) | ((unsigned)f2bf(acc[1]) << 16);
        const unsigned hi = (unsigned)f2bf(acc[2]) | ((unsigned)f2bf(acc[3]) << 16);
        orow[(t * 16 + n) * 2 + kq] = make_uint2(lo, hi);
        #pragma unroll
        for (int r = 0; r < 4; ++r) { const float v = acc[r]; sum[r] += v; ssq[r] += v * v; }
      }
      if (t < 7) {
        #pragma unroll
        for (int j = 0; j < 4; ++j) f[j] = f[j + 1];
        f[4].u4 = *(const uint4*)(row + sbase + 16 * (t + 5));
      }
    }
  }

  #pragma unroll
  for (int off = 1; off <= 8; off <<= 1)
    #pragma unroll
    for (int r = 0; r < 4; ++r) { sum[r] += __shfl_xor(sum[r], off); ssq[r] += __shfl_xor(ssq[r], off); }
  __shared__ float s_red[4][16];
  if (lane == 0)
    #pragma unroll
    for (int r = 0; r < 4; ++r) { s_red[wv][r] = sum[r]; s_red[wv][8 + r] = ssq[r]; }
  if (lane == 16)
    #pragma unroll
    for (int r = 0; r < 4; ++r) { s_red[wv][4 + r] = sum[r]; s_red[wv][12 + r] = ssq[r]; }
  __syncthreads();
  if (tid < 16)
    partial[blockIdx.x * 16 + tid] =
        s_red[0][tid] + s_red[1][tid] + s_red[2][tid] + s_red[3][tid];
}

// ---------------------------------------------------------------------------
// conv2/3: IC=8, K=15, pad=7, OC=8.  Per-wave PRIVATE LDS row staging (no
// intra-loop barriers).  BN+relu once per element; halos zeroed (pad AFTER
// BN+relu).  Fragments: ds_read_b128.
// ---------------------------------------------------------------------------
__global__ __launch_bounds__(256) void k_conv23(
    const uint4* __restrict__ inp, const float* __restrict__ wgt,
    const float* __restrict__ bias, const float* __restrict__ bnAB,
    uint2* __restrict__ outp, float* __restrict__ partial) {
  __shared__ uint4 s_row[4][144];
  const int tid = threadIdx.x;
  const int lane = tid & 63;
  const int wv = tid >> 6;
  const int gw = blockIdx.x * 4 + wv;
  const int n = lane & 15, kq = lane >> 4;

  float A[8], Bc[8];
  #pragma unroll
  for (int i = 0; i < 8; ++i) { A[i] = bnAB[2 * i]; Bc[i] = bnAB[2 * i + 1]; }

  short8 af[4];
  #pragma unroll
  for (int m = 0; m < 4; ++m) {
    U8 u;
    #pragma unroll
    for (int j = 0; j < 8; ++j) {
      const int tap = m * 4 + kq;
      const float w = (n < 8 && tap < 15) ? wgt[(n * 8 + j) * 15 + tap] : 0.f;
      u.us[j] = f2bf(w);
    }
    af[m] = u.s8;
  }
  float bias_r[4];
  #pragma unroll
  for (int r = 0; r < 4; ++r) {
    const int oo = kq * 4 + r;
    bias_r[r] = (oo < 8) ? bias[oo] : 0.f;
  }

  uint4* lds = s_row[wv];
  if (lane < 7)  lds[lane] = make_uint4(0, 0, 0, 0);
  if (lane >= 7 && lane < 16) lds[128 + lane] = make_uint4(0, 0, 0, 0);

  float sum[4] = {0, 0, 0, 0}, ssq[4] = {0, 0, 0, 0};

  for (int p = gw; p < NPIX; p += 8192) {
    const uint4* grow = inp + (size_t)p * 128;
    const uint4 v0 = grow[lane];
    const uint4 v1 = grow[64 + lane];
    lds[7 + lane]  = bn_unit(v0, A, Bc);
    lds[71 + lane] = bn_unit(v1, A, Bc);

    uint2* orow = outp + (size_t)p * 256;
    for (int t = 0; t < 8; ++t) {
      f32x4 acc = {bias_r[0], bias_r[1], bias_r[2], bias_r[3]};
      const int base = t * 16 + n + kq;
      #pragma unroll
      for (int m = 0; m < 4; ++m) {
        U8 b;
        b.u4 = lds[base + m * 4];
        acc = __builtin_amdgcn_mfma_f32_16x16x32_bf16(af[m], b.s8, acc, 0, 0, 0);
      }
      if (lane < 32) {
        const unsigned lo = (unsigned)f2bf(acc[0]) | ((unsigned)f2bf(acc[1]) << 16);
        const unsigned hi = (unsigned)f2bf(acc[2]) | ((unsigned)f2bf(acc[3]) << 16);
        orow[(t * 16 + n) * 2 + kq] = make_uint2(lo, hi);
        #pragma unroll
        for (int r = 0; r < 4; ++r) { const float v = acc[r]; sum[r] += v; ssq[r] += v * v; }
      }
    }
  }

  #pragma unroll
  for (int off = 1; off <= 8; off <<= 1)
    #pragma unroll
    for (int r = 0; r < 4; ++r) { sum[r] += __shfl_xor(sum[r], off); ssq[r] += __shfl_xor(ssq[r], off); }
  __shared__ float s_red[4][16];
  if (lane == 0)
    #pragma unroll
    for (int r = 0; r < 4; ++r) { s_red[wv][r] = sum[r]; s_red[wv][8 + r] = ssq[r]; }
  if (lane == 16)
    #pragma unroll
    for (int r = 0; r < 4; ++r) { s_red[wv][4 + r] = sum[r]; s_red[wv][12 + r] = ssq[r]; }
  __syncthreads();
  if (tid < 16)
    partial[blockIdx.x * 16 + tid] =
        s_red[0][tid] + s_red[1][tid] + s_red[2][tid] + s_red[3][tid];
}

// ---------------------------------------------------------------------------
// conv4: IC=8, K=3, pad=1, OC=1.  VALU; BN3+relu fused on load; pad taps
// contribute exactly 0.  Output bf16 (ushort).
// ---------------------------------------------------------------------------
__global__ __launch_bounds__(256) void k_conv4(
    const uint4* __restrict__ inp, const float* __restrict__ bnAB,
    const float* __restrict__ w4, const float* __restrict__ b4,
    unsigned short* __restrict__ y4b, float* __restrict__ partial) {
  const int idx = blockIdx.x * 256 + threadIdx.x;
  const int p = idx >> 7, e = idx & 127;

  float A[8], Bc[8];
  #pragma unroll
  for (int i = 0; i < 8; ++i) { A[i] = bnAB[2 * i]; Bc[i] = bnAB[2 * i + 1]; }

  float acc = b4[0];
  const uint4* row = inp + (size_t)p * 128 + e;
  #pragma unroll
  for (int kt = 0; kt < 3; ++kt) {
    const int ee = e + kt - 1;
    if (ee >= 0 && ee < E_) {
      U8 u; u.u4 = row[kt - 1];
      #pragma unroll
      for (int i = 0; i < 8; ++i) {
        const unsigned wd = u.u32[i >> 1];
        const float x = (i & 1) ? bfhi(wd) : bflo(wd);
        const float v = fmaxf(0.f, fmaf(A[i], x, Bc[i]));
        acc = fmaf(w4[i * 3 + kt], v, acc);
      }
    }
  }
  y4b[idx] = f2bf(acc);

  float s = wave_reduce_sum(acc);
  float ss = wave_reduce_sum(acc * acc);
  __shared__ float sm[4][2];
  if ((threadIdx.x & 63) == 0) { sm[threadIdx.x >> 6][0] = s; sm[threadIdx.x >> 6][1] = ss; }
  __syncthreads();
  if (threadIdx.x == 0) {
    partial[blockIdx.x * 2 + 0] = sm[0][0] + sm[1][0] + sm[2][0] + sm[3][0];
    partial[blockIdx.x * 2 + 1] = sm[0][1] + sm[1][1] + sm[2][1] + sm[3][1];
  }
}

// ---------------------------------------------------------------------------
// BN stats finalize: A = g*rsqrt(var+eps), B = beta - mu*A
// ---------------------------------------------------------------------------
__global__ __launch_bounds__(256) void k_stats(const float* __restrict__ partial,
                                               int nblk, int oc,
                                               const float* __restrict__ g,
                                               const float* __restrict__ beta,
                                               float* __restrict__ ssout) {
  const int o = blockIdx.x;
  float s = 0.f, ss = 0.f;
  for (int b = threadIdx.x; b < nblk; b += 256) {
    s  += partial[b * 2 * oc + o];
    ss += partial[b * 2 * oc + oc + o];
  }
  s = wave_reduce_sum(s);
  ss = wave_reduce_sum(ss);
  __shared__ float sm[4][2];
  if ((threadIdx.x & 63) == 0) { sm[threadIdx.x >> 6][0] = s; sm[threadIdx.x >> 6][1] = ss; }
  __syncthreads();
  if (threadIdx.x == 0) {
    s  = sm[0][0] + sm[1][0] + sm[2][0] + sm[3][0];
    ss = sm[0][1] + sm[1][1] + sm[2][1] + sm[3][1];
    const float count = (float)NS_;
    const float mu = s / count;
    const float var = fmaxf(ss / count - mu * mu, 0.f);
    const float Av = g[o] * rsqrtf(var + 1e-5f);
    ssout[2 * o] = Av;
    ssout[2 * o + 1] = beta[o] - mu * Av;
  }
}

// ---------------------------------------------------------------------------
// final: singleW = sum_e relu(A4*y4+B4); comp = singleW*(sum_e x)/E; dB.
// Per-block max -> pmax[] (no same-address atomics).
// ---------------------------------------------------------------------------
__global__ __launch_bounds__(256) void k_final(const float* __restrict__ sumI,
                                               const float* __restrict__ sumQ,
                                               const unsigned short* __restrict__ y4b,
                                               const float* __restrict__ ss4,
                                               float* __restrict__ ydb,
                                               float* __restrict__ pmax) {
  const int w = threadIdx.x >> 6;
  const int lane = threadIdx.x & 63;
  const int p = blockIdx.x * 4 + w;
  const float A = ss4[0], B = ss4[1];
  const size_t base = (size_t)p * E_;

  float sw = fmaxf(0.f, fmaf(A, bf2f(y4b[base + lane]), B)) +
             fmaxf(0.f, fmaf(A, bf2f(y4b[base + lane + 64]), B));
  sw = wave_reduce_sum(sw);

  __shared__ float s_m[4];
  if (lane == 0) {
    const float ci = sw * sumI[p] * (1.f / (float)E_);
    const float cq = sw * sumQ[p] * (1.f / (float)E_);
    const float mag = sqrtf(ci * ci + cq * cq);
    const float v = 20.f * log10f(mag + 1e-20f);
    ydb[p] = v;
    s_m[w] = v;
  }
  __syncthreads();
  if (threadIdx.x == 0)
    pmax[blockIdx.x] = fmaxf(fmaxf(s_m[0], s_m[1]), fmaxf(s_m[2], s_m[3]));
}

// k_sub with inline global-max: each block re-reduces pmax[8192]
__global__ __launch_bounds__(256) void k_sub(const float* __restrict__ ydb,
                                             const float* __restrict__ pmax,
                                             float* __restrict__ out) {
  float m = -3.4e38f;
  for (int i = threadIdx.x; i < NPIX / 4; i += 256) m = fmaxf(m, pmax[i]);
  m = wave_reduce_max(m);
  __shared__ float sm[4];
  if ((threadIdx.x & 63) == 0) sm[threadIdx.x >> 6] = m;
  __syncthreads();
  __shared__ float sgm;
  if (threadIdx.x == 0)
    sgm = fmaxf(fmaxf(sm[0], sm[1]), fmaxf(sm[2], sm[3]));
  __syncthreads();
  const int i = blockIdx.x * 256 + threadIdx.x;
  out[i] = ydb[i] - sgm;
}

// ---------------------------------------------------------------------------
// Workspace layout (bytes).  Region A is time-multiplexed:
//   x0p (27MB) -> buf2 (67MB, dead after conv3) -> y4b (8.4MB) + ydb + pmax.
// ---------------------------------------------------------------------------
static constexpr size_t OFF_A     = 0;            // 67,108,864 region
static constexpr size_t OFF_Y4    = 0;            // bf16 [NS]  (in A)
static constexpr size_t OFF_YDB   = 16777216;     // f32 [NPIX] (in A)
static constexpr size_t OFF_PMAX  = 16908288;     // f32 [8192] (in A)
static constexpr size_t OFF_BUF1  = 67108864;     // 67,108,864
static constexpr size_t OFF_SUMI  = 134217728;    // 131,072
static constexpr size_t OFF_SUMQ  = 134348800;    // 131,072
static constexpr size_t OFF_PART  = 134479872;    // 262,144
static constexpr size_t OFF_PMSQ  = 134742016;    // 16,384 (4096 f32)
static constexpr size_t OFF_SS    = 134758400;    // 256

extern "C" void kernel_launch(void* const* d_in, const int* in_sizes, int n_in,
                              void* d_out, int out_size, void* d_ws, size_t ws_size,
                              hipStream_t stream) {
  const float* idata     = (const float*)d_in[0];
  const float* qdata     = (const float*)d_in[1];
  const float* angles    = (const float*)d_in[2];
  const float* ele_pos   = (const float*)d_in[3];
  const float* time_zero = (const float*)d_in[4];
  const float* grid      = (const float*)d_in[5];
  const float* w1 = (const float*)d_in[6];  const float* b1 = (const float*)d_in[7];
  const float* g1 = (const float*)d_in[8];  const float* be1 = (const float*)d_in[9];
  const float* w2 = (const float*)d_in[10]; const float* b2 = (const float*)d_in[11];
  const float* g2 = (const float*)d_in[12]; const float* be2 = (const float*)d_in[13];
  const float* w3 = (const float*)d_in[14]; const float* b3 = (const float*)d_in[15];
  const float* g3 = (const float*)d_in[16]; const float* be3 = (const float*)d_in[17];
  const float* w4 = (const float*)d_in[18]; const float* b4 = (const float*)d_in[19];
  const float* g4 = (const float*)d_in[20]; const float* be4 = (const float*)d_in[21];

  char* ws = (char*)d_ws;
  unsigned*       x0p   = (unsigned*)(ws + OFF_A);       // [p][208] bf16-pairs
  uint4*          buf2  = (uint4*)(ws + OFF_A);          // [p][128] units
  unsigned short* y4b   = (unsigned short*)(ws + OFF_Y4);
  float*          ydb   = (float*)(ws + OFF_YDB);
  float*          pmax  = (float*)(ws + OFF_PMAX);
  uint4*          buf1  = (uint4*)(ws + OFF_BUF1);
  float*          sumI  = (float*)(ws + OFF_SUMI);
  float*          sumQ  = (float*)(ws + OFF_SUMQ);
  float*          part  = (float*)(ws + OFF_PART);
  float*          pmsq  = (float*)(ws + OFF_PMSQ);
  float*          ssAB  = (float*)(ws + OFF_SS);

  k_init<<<4096, 256, 0, stream>>>((uint4*)x0p, (const float4*)idata,
                                   (const float4*)qdata, pmsq);
  k_beamform<<<4096, 256, 0, stream>>>((const float4*)idata, (const float4*)qdata,
                                       angles, ele_pos, time_zero, grid,
                                       pmsq, x0p);

  k_conv1<<<2048, 256, 0, stream>>>(x0p, w1, b1, (uint2*)buf1, part, sumI, sumQ);
  k_stats<<<8, 256, 0, stream>>>(part, 2048, 8, g1, be1, ssAB + 0);

  k_conv23<<<2048, 256, 0, stream>>>(buf1, w2, b2, ssAB + 0, (uint2*)buf2, part);
  k_stats<<<8, 256, 0, stream>>>(part, 2048, 8, g2, be2, ssAB + 16);

  k_conv23<<<2048, 256, 0, stream>>>(buf2, w3, b3, ssAB + 16, (uint2*)buf1, part);
  k_stats<<<8, 256, 0, stream>>>(part, 2048, 8, g3, be3, ssAB + 32);

  k_conv4<<<NS_ / 256, 256, 0, stream>>>(buf1, ssAB + 32, w4, b4, y4b, part);
  k_stats<<<1, 256, 0, stream>>>(part, NS_ / 256, 1, g4, be4, ssAB + 48);

  k_final<<<NPIX / 4, 256, 0, stream>>>(sumI, sumQ, y4b, ssAB + 48, ydb, pmax);
  k_sub<<<NPIX / 256, 256, 0, stream>>>(ydb, pmax, (float*)d_out);
}